// Round 18
// baseline (629.652 us; speedup 1.0000x reference)
//
#include <hip/hip_runtime.h>

#define METAc 3
#define Nn 50000
#define Ee 640000
#define CHUNK 1024
#define NCH 49   // ceil(Nn/CHUNK)
#define NRANGE 1563   // nodes per fill range
#define NRG 32        // ranges per graph (32*1563 >= 50000)
#define FCAP 24576    // LDS edge capacity per segment (exp 20006, +32 sigma)

typedef unsigned int uint;
typedef unsigned short ushort;
typedef unsigned char uchar;
typedef __attribute__((ext_vector_type(8))) short bf16x8;
typedef __attribute__((ext_vector_type(4))) float f32x4;
typedef __attribute__((ext_vector_type(2))) float f32x2;
typedef __attribute__((ext_vector_type(4))) uint uint4v;

// decode 2 packed OCP-fp8(e4m3) from low/high word of a uint -> float2 (1 VALU op)
#define CVT8LO(w) ((f32x2)__builtin_amdgcn_cvt_pk_f32_fp8((w), false))
#define CVT8HI(w) ((f32x2)__builtin_amdgcn_cvt_pk_f32_fp8((w), true))

__device__ __forceinline__ float bf2f(uint u16) {
    union { uint u; float f; } v; v.u = u16 << 16; return v.f;
}
__device__ __forceinline__ uint f2bf(float f) {
    union { float f; uint u; } v; v.f = f;
    return (v.u + 0x7fffu + ((v.u >> 16) & 1u)) >> 16;
}
__device__ __forceinline__ uchar f2fp8(float f) {
    return (uchar)(__builtin_amdgcn_cvt_pk_fp8_f32(f, f, 0u, false) & 0xffu);
}
__device__ __forceinline__ f32x2 up2(uint u) {
    union { uint2 u2; f32x2 f; } cv;
    cv.u2.x = u << 16;
    cv.u2.y = u & 0xffff0000u;
    return cv.f;
}
__device__ __forceinline__ f32x4 mfma16(bf16x8 a, bf16x8 b, f32x4 c) {
    return __builtin_amdgcn_mfma_f32_16x16x32_bf16(a, b, c, 0, 0, 0);
}
__device__ __forceinline__ uint4v nt_load4(const void* p) {
    return __builtin_nontemporal_load((const uint4v*)p);
}

// ================= CSR build =================
__global__ __launch_bounds__(256) void k_count(const int* __restrict__ ei, int* __restrict__ cnt,
                                               uint* __restrict__ packed) {
    int idx = blockIdx.x * 256 + threadIdx.x;
    if (idx >= METAc * (Ee / 4)) return;
    int m = idx / (Ee / 4), e4 = idx - m * (Ee / 4);
    const int* base = ei + (size_t)m * 2 * Ee;
    uint4v d = nt_load4(base + Ee + e4 * 4);
    uint4v s = nt_load4(base + e4 * 4);
    int* cm = cnt + m * Nn;
    atomicAdd(cm + (int)d.x, 1);
    atomicAdd(cm + (int)d.y, 1);
    atomicAdd(cm + (int)d.z, 1);
    atomicAdd(cm + (int)d.w, 1);
    uint4v p;
    p.x = (s.x & 0xffffu) | (d.x << 16);
    p.y = (s.y & 0xffffu) | (d.y << 16);
    p.z = (s.z & 0xffffu) | (d.z << 16);
    p.w = (s.w & 0xffffu) | (d.w << 16);
    *(uint4v*)(packed + (size_t)m * Ee + e4 * 4) = p;
}

__global__ __launch_bounds__(1024) void k_chunksum(const int* __restrict__ cnt, int* __restrict__ csum) {
    int m = blockIdx.x / NCH, ch = blockIdx.x - m * NCH;
    int tid = threadIdx.x;
    int i = ch * CHUNK + tid;
    int v = (i < Nn) ? cnt[m * Nn + i] : 0;
    #pragma unroll
    for (int o = 1; o < 64; o <<= 1) v += __shfl_xor(v, o);
    __shared__ int ws_[16];
    int lane = tid & 63, w = tid >> 6;
    if (lane == 0) ws_[w] = v;
    __syncthreads();
    if (tid == 0) {
        int s = 0;
        #pragma unroll
        for (int k = 0; k < 16; k++) s += ws_[k];
        csum[m * 64 + ch] = s;
    }
}

__global__ __launch_bounds__(256) void k_chunkscan(int* __restrict__ csum) {
    int tid = threadIdx.x;
    int w = tid >> 6, lane = tid & 63;
    if (w >= METAc) return;
    int v = (lane < NCH) ? csum[w * 64 + lane] : 0;
    int orig = v;
    #pragma unroll
    for (int o = 1; o < 64; o <<= 1) { int t = __shfl_up(v, o); if (lane >= o) v += t; }
    if (lane < NCH) csum[w * 64 + lane] = v - orig;
}

__global__ __launch_bounds__(1024) void k_scan(const int* __restrict__ cnt, const int* __restrict__ csum,
                                               int* __restrict__ off, float* __restrict__ inv) {
    int m = blockIdx.x / NCH, ch = blockIdx.x - m * NCH;
    int tid = threadIdx.x;
    int i = ch * CHUNK + tid;
    int c = (i < Nn) ? cnt[m * Nn + i] : 0;
    int lane = tid & 63, w = tid >> 6;
    int v = c;
    #pragma unroll
    for (int o = 1; o < 64; o <<= 1) { int t = __shfl_up(v, o); if (lane >= o) v += t; }
    __shared__ int ws_[16];
    if (lane == 63) ws_[w] = v;
    __syncthreads();
    if (tid < 16) {
        int s = ws_[tid];
        #pragma unroll
        for (int o = 1; o < 16; o <<= 1) { int t = __shfl_up(s, o); if (lane >= o) s += t; }
        ws_[tid] = s;
    }
    __syncthreads();
    int base = (w > 0) ? ws_[w - 1] : 0;
    if (i < Nn) {
        int g = csum[m * 64 + ch] + base + v - c;
        off[m * Nn + i] = g;
        inv[m * Nn + i] = 1.0f / fmaxf((float)c, 1.0f);
    }
}

// ============ LDS-binned CSR fill ============
// Workgroup = (graph m, dst range of NRANGE nodes). Streams the graph's packed
// edge list (L2/L3-shared across the 32 range-workgroups of that graph), bins
// matching edges into an LDS segment via LDS-atomic cursors, then flushes the
// segment to esrc fully coalesced. Eliminates the scattered-global-write
// amplification (70 MB -> ~8 MB) and all global cursor atomics.
__global__ __launch_bounds__(256) void k_fillb(const uint* __restrict__ packed,
                                               const int* __restrict__ off,
                                               ushort* __restrict__ esrc) {
    const int m = blockIdx.x / NRG;
    const int rg = blockIdx.x - m * NRG;
    const int r0 = rg * NRANGE;
    const int r1 = (r0 + NRANGE < Nn) ? r0 + NRANGE : Nn;
    const int nr = r1 - r0;

    __shared__ ushort seg[FCAP];
    __shared__ int curs[NRANGE];

    const int* offm = off + m * Nn;
    const int off0 = offm[r0];
    const int segend = (r1 < Nn) ? offm[r1] : Ee;
    const int seglen = segend - off0;
    const bool direct = seglen > FCAP;   // safety fallback (never expected)

    for (int i = threadIdx.x; i < nr; i += 256)
        curs[i] = offm[r0 + i] - off0;
    __syncthreads();

    const uint* pm = packed + (size_t)m * Ee;
    ushort* em = esrc + (size_t)m * Ee;

    for (int e4 = threadIdx.x; e4 < Ee / 4; e4 += 256) {
        uint4v p = *(const uint4v*)(pm + e4 * 4);   // cached: 32 wgs share this stream
        int d;
        d = (int)(p.x >> 16);
        if (d >= r0 && d < r1) {
            int pos = atomicAdd(&curs[d - r0], 1);
            if (direct) em[off0 + pos] = (ushort)(p.x & 0xffffu); else seg[pos] = (ushort)(p.x & 0xffffu);
        }
        d = (int)(p.y >> 16);
        if (d >= r0 && d < r1) {
            int pos = atomicAdd(&curs[d - r0], 1);
            if (direct) em[off0 + pos] = (ushort)(p.y & 0xffffu); else seg[pos] = (ushort)(p.y & 0xffffu);
        }
        d = (int)(p.z >> 16);
        if (d >= r0 && d < r1) {
            int pos = atomicAdd(&curs[d - r0], 1);
            if (direct) em[off0 + pos] = (ushort)(p.z & 0xffffu); else seg[pos] = (ushort)(p.z & 0xffffu);
        }
        d = (int)(p.w >> 16);
        if (d >= r0 && d < r1) {
            int pos = atomicAdd(&curs[d - r0], 1);
            if (direct) em[off0 + pos] = (ushort)(p.w & 0xffffu); else seg[pos] = (ushort)(p.w & 0xffffu);
        }
    }
    __syncthreads();

    if (!direct) {
        for (int i = threadIdx.x; i < seglen; i += 256)
            em[off0 + i] = seg[i];
    }
}

// ============ weight prep ============
__global__ __launch_bounds__(256) void k_wcat(
    const float* __restrict__ W1l, const float* __restrict__ W1r,
    const float* __restrict__ W2l, const float* __restrict__ W2r,
    ushort* __restrict__ Wcat1, ushort* __restrict__ Wcat2)
{
    int idx = blockIdx.x * 256 + threadIdx.x;
    if (idx >= METAc * 384 * 128) return;
    int m = idx / (384 * 128);
    int rem = idx - m * 384 * 128;
    int j = rem >> 7;
    int k = rem & 127;
    if (j < 256) {
        float v = (j < 128) ? W1l[((size_t)m * 128 + k) * 128 + j]
                            : W1r[((size_t)m * 128 + k) * 128 + (j - 128)];
        Wcat1[((size_t)m * 256 + j) * 128 + k] = (ushort)f2bf(v);
    } else {
        int j2 = j - 256;
        float v = (j2 < 64) ? W2l[((size_t)m * 128 + k) * 64 + j2]
                            : W2r[((size_t)m * 128 + k) * 64 + (j2 - 64)];
        Wcat2[((size_t)m * 128 + j2) * 128 + k] = (ushort)f2bf(v);
    }
}

// ============ MFMA GEMM1: t1 (fp8) and r1 (bf16, +b1) = x @ {W1l, W1r} ============
__global__ __launch_bounds__(256) void k_mfma1(
    const float* __restrict__ x, const ushort* __restrict__ Wcat1,
    const float* __restrict__ b1, uchar* __restrict__ t1, ushort* __restrict__ r1)
{
    const int m = blockIdx.y;
    const int row0 = blockIdx.x * 128;
    const int tid = threadIdx.x;
    const int lane = tid & 63, w = tid >> 6;
    const int wr = w >> 1, wc = w & 1;

    __shared__ ushort As[128][136];   // 272B rows: 2-way bank aliasing only
    __shared__ ushort Bs[128][136];

    const float* Am = x + (size_t)m * Nn * 128;

    #pragma unroll
    for (int i = 0; i < 16; i++) {
        int f4 = tid + i * 256;
        int row = f4 >> 5, c4 = f4 & 31;
        int gr = row0 + row; if (gr >= Nn) gr = Nn - 1;
        float4 v = *(const float4*)(Am + (size_t)gr * 128 + c4 * 4);
        uint lo = f2bf(v.x) | (f2bf(v.y) << 16);
        uint hi = f2bf(v.z) | (f2bf(v.w) << 16);
        *(uint2*)&As[row][c4 * 4] = make_uint2(lo, hi);
    }

    for (int z = 0; z < 2; z++) {
        const ushort* Bm = Wcat1 + ((size_t)m * 256 + (size_t)z * 128) * 128;
        if (z) __syncthreads();
        #pragma unroll
        for (int i = 0; i < 8; i++) {
            int c8 = tid + i * 256;
            int row = c8 >> 4, c = c8 & 15;
            *(bf16x8*)&Bs[row][c * 8] = *(const bf16x8*)(Bm + (size_t)row * 128 + c * 8);
        }
        __syncthreads();

        f32x4 acc[4][4];
        #pragma unroll
        for (int i = 0; i < 4; i++)
            #pragma unroll
            for (int j = 0; j < 4; j++) acc[i][j] = (f32x4){0.f, 0.f, 0.f, 0.f};

        #pragma unroll
        for (int ks = 0; ks < 4; ks++) {
            bf16x8 a[4], b[4];
            #pragma unroll
            for (int i = 0; i < 4; i++)
                a[i] = *(const bf16x8*)&As[wr * 64 + i * 16 + (lane & 15)][ks * 32 + (lane >> 4) * 8];
            #pragma unroll
            for (int j = 0; j < 4; j++)
                b[j] = *(const bf16x8*)&Bs[wc * 64 + j * 16 + (lane & 15)][ks * 32 + (lane >> 4) * 8];
            #pragma unroll
            for (int i = 0; i < 4; i++)
                #pragma unroll
                for (int j = 0; j < 4; j++)
                    acc[i][j] = mfma16(a[i], b[j], acc[i][j]);
        }

        if (z == 0) {
            uchar* outp = t1 + (size_t)m * Nn * 128;
            #pragma unroll
            for (int j = 0; j < 4; j++) {
                int col = wc * 64 + j * 16 + (lane & 15);
                #pragma unroll
                for (int i = 0; i < 4; i++) {
                    #pragma unroll
                    for (int q = 0; q < 4; q++) {
                        int row = row0 + wr * 64 + i * 16 + (lane >> 4) * 4 + q;
                        if (row < Nn)
                            outp[(size_t)row * 128 + col] = f2fp8(acc[i][j][q]);
                    }
                }
            }
        } else {
            ushort* outp = r1 + (size_t)m * Nn * 128;
            #pragma unroll
            for (int j = 0; j < 4; j++) {
                int col = wc * 64 + j * 16 + (lane & 15);
                float bias = b1[m * 128 + col];
                #pragma unroll
                for (int i = 0; i < 4; i++) {
                    #pragma unroll
                    for (int q = 0; q < 4; q++) {
                        int row = row0 + wr * 64 + i * 16 + (lane >> 4) * 4 + q;
                        if (row < Nn)
                            outp[(size_t)row * 128 + col] = (ushort)f2bf(acc[i][j][q] + bias);
                    }
                }
            }
        }
    }
}

// ============ MFMA GEMM2: t2 (bf16) / r2 (bf16, +b2) = h @ Wcat2 ============
__global__ __launch_bounds__(256) void k_mfma2(
    const ushort* __restrict__ h, const ushort* __restrict__ Wcat2,
    const float* __restrict__ b2, ushort* __restrict__ t2, ushort* __restrict__ r2)
{
    const int m = blockIdx.y;
    const int row0 = blockIdx.x * 128;
    const int tid = threadIdx.x;
    const int lane = tid & 63, w = tid >> 6;
    const int wr = w >> 1, wc = w & 1;

    __shared__ ushort As[128][136];
    __shared__ ushort Bs[128][136];

    const ushort* Am = h + (size_t)m * Nn * 128;
    const ushort* Bm = Wcat2 + (size_t)m * 128 * 128;

    #pragma unroll
    for (int i = 0; i < 8; i++) {
        int c8 = tid + i * 256;
        int row = c8 >> 4, c = c8 & 15;
        int gr = row0 + row; if (gr >= Nn) gr = Nn - 1;
        *(bf16x8*)&As[row][c * 8] = *(const bf16x8*)(Am + (size_t)gr * 128 + c * 8);
    }
    #pragma unroll
    for (int i = 0; i < 8; i++) {
        int c8 = tid + i * 256;
        int row = c8 >> 4, c = c8 & 15;
        *(bf16x8*)&Bs[row][c * 8] = *(const bf16x8*)(Bm + (size_t)row * 128 + c * 8);
    }
    __syncthreads();

    f32x4 acc[4][4];
    #pragma unroll
    for (int i = 0; i < 4; i++)
        #pragma unroll
        for (int j = 0; j < 4; j++) acc[i][j] = (f32x4){0.f, 0.f, 0.f, 0.f};

    #pragma unroll
    for (int ks = 0; ks < 4; ks++) {
        bf16x8 a[4], b[4];
        #pragma unroll
        for (int i = 0; i < 4; i++)
            a[i] = *(const bf16x8*)&As[wr * 64 + i * 16 + (lane & 15)][ks * 32 + (lane >> 4) * 8];
        #pragma unroll
        for (int j = 0; j < 4; j++)
            b[j] = *(const bf16x8*)&Bs[wc * 64 + j * 16 + (lane & 15)][ks * 32 + (lane >> 4) * 8];
        #pragma unroll
        for (int i = 0; i < 4; i++)
            #pragma unroll
            for (int j = 0; j < 4; j++)
                acc[i][j] = mfma16(a[i], b[j], acc[i][j]);
    }

    ushort* outp = (wc ? r2 : t2) + (size_t)m * Nn * 64;
    #pragma unroll
    for (int j = 0; j < 4; j++) {
        int cl = j * 16 + (lane & 15);
        float bias = wc ? b2[m * 64 + cl] : 0.0f;
        #pragma unroll
        for (int i = 0; i < 4; i++) {
            #pragma unroll
            for (int q = 0; q < 4; q++) {
                int row = row0 + wr * 64 + i * 16 + (lane >> 4) * 4 + q;
                if (row < Nn)
                    outp[(size_t)row * 64 + cl] = (ushort)f2bf(acc[i][j][q] + bias);
            }
        }
    }
}

// ============ agg1: h = ELU(mean-gather(t1 fp8) + r1), bf16 out ============
// One 8-lane group per NODE (8 nodes/wave).
__global__ __launch_bounds__(256) void k_agg_elu(
    const uchar* __restrict__ t1, const ushort* __restrict__ r1,
    const int* __restrict__ off, const int* __restrict__ cnt,
    const float* __restrict__ inv, const ushort* __restrict__ esrc,
    ushort* __restrict__ h)
{
    int lane = threadIdx.x & 63;
    int grp = lane >> 3;      // node slot within wave
    int sub = lane & 7;       // 16B column chunk (16 fp8)
    int node = ((blockIdx.x * 256 + threadIdx.x) >> 6) * 8 + grp;
    if (node >= METAc * Nn) return;
    int m = node / Nn, n = node - m * Nn;
    int start = off[m * Nn + n];
    int c = cnt[m * Nn + n];
    const ushort* es = esrc + (size_t)m * Ee + start;
    const uchar* tm = t1 + (size_t)m * Nn * 128;

    f32x2 a[8];
    #pragma unroll
    for (int k = 0; k < 8; k++) a[k] = (f32x2){0.f, 0.f};

    int e = 0;
    for (; e + 1 < c; e += 2) {
        int s0 = es[e], s1 = es[e + 1];
        uint4 v0 = *(const uint4*)(tm + (size_t)s0 * 128 + sub * 16);
        uint4 v1 = *(const uint4*)(tm + (size_t)s1 * 128 + sub * 16);
        a[0] += CVT8LO(v0.x); a[1] += CVT8HI(v0.x);
        a[2] += CVT8LO(v0.y); a[3] += CVT8HI(v0.y);
        a[4] += CVT8LO(v0.z); a[5] += CVT8HI(v0.z);
        a[6] += CVT8LO(v0.w); a[7] += CVT8HI(v0.w);
        a[0] += CVT8LO(v1.x); a[1] += CVT8HI(v1.x);
        a[2] += CVT8LO(v1.y); a[3] += CVT8HI(v1.y);
        a[4] += CVT8LO(v1.z); a[5] += CVT8HI(v1.z);
        a[6] += CVT8LO(v1.w); a[7] += CVT8HI(v1.w);
    }
    if (e < c) {
        int s0 = es[e];
        uint4 v0 = *(const uint4*)(tm + (size_t)s0 * 128 + sub * 16);
        a[0] += CVT8LO(v0.x); a[1] += CVT8HI(v0.x);
        a[2] += CVT8LO(v0.y); a[3] += CVT8HI(v0.y);
        a[4] += CVT8LO(v0.z); a[5] += CVT8HI(v0.z);
        a[6] += CVT8LO(v0.w); a[7] += CVT8HI(v0.w);
    }

    float iv = inv[m * Nn + n];
    const uint* rrow = (const uint*)(r1 + ((size_t)m * Nn + n) * 128);
    uint4 rv0 = *(const uint4*)(rrow + sub * 8);
    uint4 rv1 = *(const uint4*)(rrow + sub * 8 + 4);
    uint rw[8] = {rv0.x, rv0.y, rv0.z, rv0.w, rv1.x, rv1.y, rv1.z, rv1.w};
    uint o[8];
    #pragma unroll
    for (int k = 0; k < 8; k++) {
        float z0 = a[k].x * iv + bf2f(rw[k] & 0xffffu);
        float z1 = a[k].y * iv + bf2f(rw[k] >> 16);
        z0 = z0 > 0.0f ? z0 : (__expf(z0) - 1.0f);
        z1 = z1 > 0.0f ? z1 : (__expf(z1) - 1.0f);
        o[k] = f2bf(z0) | (f2bf(z1) << 16);
    }
    uint* hrow = (uint*)(h + ((size_t)m * Nn + n) * 128) + sub * 8;
    *(uint4*)hrow       = make_uint4(o[0], o[1], o[2], o[3]);
    *(uint4*)(hrow + 4) = make_uint4(o[4], o[5], o[6], o[7]);
}

// ============ agg2: out = log_softmax(mean-gather(t2 bf16) + r2) ============
__global__ __launch_bounds__(256) void k_agg_lsm(
    const ushort* __restrict__ t2, const ushort* __restrict__ r2,
    const int* __restrict__ off, const int* __restrict__ cnt,
    const float* __restrict__ inv, const ushort* __restrict__ esrc,
    float* __restrict__ out)
{
    int lane = threadIdx.x & 63;
    int grp = lane >> 3;
    int sub = lane & 7;       // 16B chunk = 8 bf16 cols
    int node = ((blockIdx.x * 256 + threadIdx.x) >> 6) * 8 + grp;
    if (node >= METAc * Nn) return;
    int m = node / Nn, n = node - m * Nn;
    int start = off[m * Nn + n];
    int c = cnt[m * Nn + n];
    const ushort* es = esrc + (size_t)m * Ee + start;
    const ushort* tm = t2 + (size_t)m * Nn * 64;

    f32x2 a[4];
    #pragma unroll
    for (int k = 0; k < 4; k++) a[k] = (f32x2){0.f, 0.f};

    int e = 0;
    for (; e + 1 < c; e += 2) {
        int s0 = es[e], s1 = es[e + 1];
        uint4 v0 = *(const uint4*)(tm + (size_t)s0 * 64 + sub * 8);
        uint4 v1 = *(const uint4*)(tm + (size_t)s1 * 64 + sub * 8);
        a[0] += up2(v0.x); a[1] += up2(v0.y); a[2] += up2(v0.z); a[3] += up2(v0.w);
        a[0] += up2(v1.x); a[1] += up2(v1.y); a[2] += up2(v1.z); a[3] += up2(v1.w);
    }
    if (e < c) {
        int s0 = es[e];
        uint4 v0 = *(const uint4*)(tm + (size_t)s0 * 64 + sub * 8);
        a[0] += up2(v0.x); a[1] += up2(v0.y); a[2] += up2(v0.z); a[3] += up2(v0.w);
    }

    float iv = inv[m * Nn + n];
    uint4 rv = *(const uint4*)(r2 + ((size_t)m * Nn + n) * 64 + sub * 8);
    uint rr[4] = {rv.x, rv.y, rv.z, rv.w};
    float z[8];
    #pragma unroll
    for (int k = 0; k < 4; k++) {
        z[2 * k]     = a[k].x * iv + bf2f(rr[k] & 0xffffu);
        z[2 * k + 1] = a[k].y * iv + bf2f(rr[k] >> 16);
    }
    float mx = z[0];
    #pragma unroll
    for (int k = 1; k < 8; k++) mx = fmaxf(mx, z[k]);
    #pragma unroll
    for (int o = 1; o <= 4; o <<= 1) mx = fmaxf(mx, __shfl_xor(mx, o));
    float s = 0.0f;
    #pragma unroll
    for (int k = 0; k < 8; k++) s += __expf(z[k] - mx);
    #pragma unroll
    for (int o = 1; o <= 4; o <<= 1) s += __shfl_xor(s, o);
    float lse = mx + __logf(s);
    float* op = out + ((size_t)m * Nn + n) * 64 + sub * 8;
    *(float4*)op       = make_float4(z[0] - lse, z[1] - lse, z[2] - lse, z[3] - lse);
    *(float4*)(op + 4) = make_float4(z[4] - lse, z[5] - lse, z[6] - lse, z[7] - lse);
}

extern "C" void kernel_launch(void* const* d_in, const int* in_sizes, int n_in,
                              void* d_out, int out_size, void* d_ws, size_t ws_size,
                              hipStream_t stream) {
    const float* meta_x = (const float*)d_in[0];
    const int*   ei     = (const int*)d_in[1];
    const float* W1l    = (const float*)d_in[2];
    const float* W1r    = (const float*)d_in[3];
    const float* b1     = (const float*)d_in[4];
    const float* W2l    = (const float*)d_in[5];
    const float* W2r    = (const float*)d_in[6];
    const float* b2     = (const float*)d_in[7];
    float* out = (float*)d_out;

    const size_t nN = (size_t)METAc * Nn;

    float* inv  = (float*)d_ws;
    int*   cnt  = (int*)(inv + nN);
    int*   off  = cnt + nN;
    int*   csum = off + nN;
    uint*  packed = (uint*)(csum + 64 * METAc);         // META*E packed (src|dst<<16)
    ushort* esrc = (ushort*)(packed + (size_t)METAc * Ee);
    uchar* t1   = (uchar*)(esrc + (size_t)METAc * Ee);  // fp8 e4m3, [nN][128]
    ushort* r1  = (ushort*)(t1 + nN * 128);
    ushort* h   = r1 + nN * 128;
    ushort* t2  = h + nN * 128;                         // bf16, [nN][64]
    ushort* r2  = t2 + nN * 64;
    ushort* Wcat1 = r2 + nN * 64;                       // META*256*128
    ushort* Wcat2 = Wcat1 + (size_t)METAc * 256 * 128;  // META*128*128

    (void)hipMemsetAsync(cnt, 0, nN * sizeof(int), stream);
    k_count<<<(METAc * (Ee / 4) + 255) / 256, 256, 0, stream>>>(ei, cnt, packed);
    k_chunksum<<<METAc * NCH, 1024, 0, stream>>>(cnt, csum);
    k_chunkscan<<<1, 256, 0, stream>>>(csum);
    k_scan<<<METAc * NCH, 1024, 0, stream>>>(cnt, csum, off, inv);
    k_fillb<<<METAc * NRG, 256, 0, stream>>>(packed, off, esrc);
    k_wcat<<<(METAc * 384 * 128 + 255) / 256, 256, 0, stream>>>(W1l, W1r, W2l, W2r, Wcat1, Wcat2);

    k_mfma1<<<dim3((Nn + 127) / 128, METAc), 256, 0, stream>>>(meta_x, Wcat1, b1, t1, r1);
    k_agg_elu<<<(METAc * Nn / 8 + 255) / 256 * 64, 256, 0, stream>>>(t1, r1, off, cnt, inv, esrc, h);
    k_mfma2<<<dim3((Nn + 127) / 128, METAc), 256, 0, stream>>>(h, Wcat2, b2, t2, r2);
    k_agg_lsm<<<(METAc * Nn / 8 + 255) / 256 * 64, 256, 0, stream>>>(t2, r2, off, cnt, inv, esrc, out);
}

// Round 19
// 254.362 us; speedup vs baseline: 2.4754x; 2.4754x over previous
//
#include <hip/hip_runtime.h>

#define METAc 3
#define Nn 50000
#define Ee 640000
#define BKT 200      // dst buckets per graph
#define BN 250       // nodes per bucket (200*250 = 50000 exact)
#define NCHK 625     // 1024-edge chunks per graph (625*1024 = 640000 exact)
#define SEGCAP 4608  // LDS edge cap per bucket (mean 3200, sigma 57 -> +24 sigma)

typedef unsigned int uint;
typedef unsigned short ushort;
typedef unsigned char uchar;
typedef __attribute__((ext_vector_type(8))) short bf16x8;
typedef __attribute__((ext_vector_type(4))) float f32x4;
typedef __attribute__((ext_vector_type(2))) float f32x2;
typedef __attribute__((ext_vector_type(4))) uint uint4v;

#define CVT8LO(w) ((f32x2)__builtin_amdgcn_cvt_pk_f32_fp8((w), false))
#define CVT8HI(w) ((f32x2)__builtin_amdgcn_cvt_pk_f32_fp8((w), true))

__device__ __forceinline__ float bf2f(uint u16) {
    union { uint u; float f; } v; v.u = u16 << 16; return v.f;
}
__device__ __forceinline__ uint f2bf(float f) {
    union { float f; uint u; } v; v.f = f;
    return (v.u + 0x7fffu + ((v.u >> 16) & 1u)) >> 16;
}
__device__ __forceinline__ uchar f2fp8(float f) {
    return (uchar)(__builtin_amdgcn_cvt_pk_fp8_f32(f, f, 0u, false) & 0xffu);
}
__device__ __forceinline__ f32x2 up2(uint u) {
    union { uint2 u2; f32x2 f; } cv;
    cv.u2.x = u << 16;
    cv.u2.y = u & 0xffff0000u;
    return cv.f;
}
__device__ __forceinline__ f32x4 mfma16(bf16x8 a, bf16x8 b, f32x4 c) {
    return __builtin_amdgcn_mfma_f32_16x16x32_bf16(a, b, c, 0, 0, 0);
}
__device__ __forceinline__ uint4v nt_load4(const void* p) {
    return __builtin_nontemporal_load((const uint4v*)p);
}

// ===== 1) pack + per-chunk bucket histogram (no global atomics) =====
__global__ __launch_bounds__(256) void k_packhist(const int* __restrict__ ei,
                                                  uint* __restrict__ packed,
                                                  int* __restrict__ ghist) {
    const int m = blockIdx.x / NCHK;
    const int b = blockIdx.x - m * NCHK;
    const int t = threadIdx.x;
    __shared__ int hist[BKT];
    if (t < BKT) hist[t] = 0;
    __syncthreads();

    const int e4 = b * 256 + t;                 // uint4 index within graph
    const int* base = ei + (size_t)m * 2 * Ee;
    uint4v d = nt_load4(base + Ee + e4 * 4);
    uint4v s = nt_load4(base + e4 * 4);
    uint4v p;
    p.x = (s.x & 0xffffu) | (d.x << 16);
    p.y = (s.y & 0xffffu) | (d.y << 16);
    p.z = (s.z & 0xffffu) | (d.z << 16);
    p.w = (s.w & 0xffffu) | (d.w << 16);
    *(uint4v*)(packed + (size_t)m * Ee + e4 * 4) = p;
    atomicAdd(&hist[(int)(d.x) / BN], 1);
    atomicAdd(&hist[(int)(d.y) / BN], 1);
    atomicAdd(&hist[(int)(d.z) / BN], 1);
    atomicAdd(&hist[(int)(d.w) / BN], 1);
    __syncthreads();
    if (t < BKT) ghist[((size_t)m * NCHK + b) * BKT + t] = hist[t];
}

// ===== 2) per-(m,bucket) exclusive scan over chunks -> sofs, totals =====
__global__ __launch_bounds__(1024) void k_bscan(const int* __restrict__ ghist,
                                                int* __restrict__ sofs,
                                                int* __restrict__ totals) {
    const int m = blockIdx.x / BKT;
    const int k = blockIdx.x - m * BKT;
    const int t = threadIdx.x;
    __shared__ int sc[1024];
    int v = (t < NCHK) ? ghist[((size_t)m * NCHK + t) * BKT + k] : 0;
    sc[t] = v;
    __syncthreads();
    for (int st = 1; st < 1024; st <<= 1) {
        int add = (t >= st) ? sc[t - st] : 0;
        __syncthreads();
        sc[t] += add;
        __syncthreads();
    }
    if (t < NCHK) sofs[((size_t)m * BKT + k) * NCHK + t] = sc[t] - v;
    if (t == NCHK - 1) totals[m * BKT + k] = sc[t];
}

// ===== 3) per-graph scan of bucket totals -> bucket bases =====
__global__ __launch_bounds__(256) void k_bbase(const int* __restrict__ totals,
                                               int* __restrict__ bbase) {
    const int m = blockIdx.x;
    const int t = threadIdx.x;
    __shared__ int sc[256];
    int v = (t < BKT) ? totals[m * BKT + t] : 0;
    sc[t] = v;
    __syncthreads();
    for (int st = 1; st < 256; st <<= 1) {
        int add = (t >= st) ? sc[t - st] : 0;
        __syncthreads();
        sc[t] += add;
        __syncthreads();
    }
    if (t < BKT) bbase[m * BKT + t] = sc[t] - v;
}

// ===== 4) bucket partition: packed -> mid (LDS cursors, no global atomics) =====
__global__ __launch_bounds__(256) void k_scatterP(const uint* __restrict__ packed,
                                                  const int* __restrict__ sofs,
                                                  const int* __restrict__ bbase,
                                                  uint* __restrict__ mid) {
    const int m = blockIdx.x / NCHK;
    const int b = blockIdx.x - m * NCHK;
    const int t = threadIdx.x;
    __shared__ int curs[BKT];
    if (t < BKT)
        curs[t] = bbase[m * BKT + t] + sofs[((size_t)m * BKT + t) * NCHK + b];
    __syncthreads();

    const int e4 = b * 256 + t;
    uint4v p = *(const uint4v*)(packed + (size_t)m * Ee + e4 * 4);
    uint* mm = mid + (size_t)m * Ee;
    int kk, pos;
    kk = (int)(p.x >> 16) / BN; pos = atomicAdd(&curs[kk], 1); mm[pos] = p.x;
    kk = (int)(p.y >> 16) / BN; pos = atomicAdd(&curs[kk], 1); mm[pos] = p.y;
    kk = (int)(p.z >> 16) / BN; pos = atomicAdd(&curs[kk], 1); mm[pos] = p.z;
    kk = (int)(p.w >> 16) / BN; pos = atomicAdd(&curs[kk], 1); mm[pos] = p.w;
}

// ===== 5) per-bucket bin: mid -> esrc (coalesced), also off/cnt/inv =====
__global__ __launch_bounds__(256) void k_binb(const uint* __restrict__ mid,
                                              const int* __restrict__ bbase,
                                              int* __restrict__ off,
                                              int* __restrict__ cnt,
                                              float* __restrict__ inv,
                                              ushort* __restrict__ esrc) {
    const int m = blockIdx.x / BKT;
    const int k = blockIdx.x - m * BKT;
    const int t = threadIdx.x;
    const int n0 = k * BN;
    const int sbase = bbase[m * BKT + k];
    const int send = (k < BKT - 1) ? bbase[m * BKT + k + 1] : Ee;
    const int seglen = send - sbase;

    __shared__ uint seg[SEGCAP];
    __shared__ ushort outs[SEGCAP];
    __shared__ int lcnt[BN];
    __shared__ int lcur[BN];
    __shared__ int sc[256];

    const uint* mm = mid + (size_t)m * Ee + sbase;
    ushort* em = esrc + (size_t)m * Ee + sbase;
    const bool fits = seglen <= SEGCAP;

    if (fits)
        for (int i = t; i < seglen; i += 256) seg[i] = mm[i];
    if (t < BN) lcnt[t] = 0;
    __syncthreads();

    for (int i = t; i < seglen; i += 256) {
        uint p = fits ? seg[i] : mm[i];
        atomicAdd(&lcnt[(int)(p >> 16) - n0], 1);
    }
    __syncthreads();

    // exclusive scan of lcnt over BN (<=250) nodes
    int v = (t < BN) ? lcnt[t] : 0;
    sc[t] = v;
    __syncthreads();
    for (int st = 1; st < 256; st <<= 1) {
        int add = (t >= st) ? sc[t - st] : 0;
        __syncthreads();
        sc[t] += add;
        __syncthreads();
    }
    if (t < BN) {
        int excl = sc[t] - v;
        lcur[t] = excl;
        int node = m * Nn + n0 + t;
        off[node] = sbase + excl;
        cnt[node] = v;
        inv[node] = 1.0f / fmaxf((float)v, 1.0f);
    }
    __syncthreads();

    if (fits) {
        for (int i = t; i < seglen; i += 256) {
            uint p = seg[i];
            int pos = atomicAdd(&lcur[(int)(p >> 16) - n0], 1);
            outs[pos] = (ushort)(p & 0xffffu);
        }
        __syncthreads();
        for (int i = t; i < seglen; i += 256) em[i] = outs[i];
    } else {
        for (int i = t; i < seglen; i += 256) {
            uint p = mm[i];
            int pos = atomicAdd(&lcur[(int)(p >> 16) - n0], 1);
            em[pos] = (ushort)(p & 0xffffu);
        }
    }
}

// ============ weight prep ============
__global__ __launch_bounds__(256) void k_wcat(
    const float* __restrict__ W1l, const float* __restrict__ W1r,
    const float* __restrict__ W2l, const float* __restrict__ W2r,
    ushort* __restrict__ Wcat1, ushort* __restrict__ Wcat2)
{
    int idx = blockIdx.x * 256 + threadIdx.x;
    if (idx >= METAc * 384 * 128) return;
    int m = idx / (384 * 128);
    int rem = idx - m * 384 * 128;
    int j = rem >> 7;
    int k = rem & 127;
    if (j < 256) {
        float v = (j < 128) ? W1l[((size_t)m * 128 + k) * 128 + j]
                            : W1r[((size_t)m * 128 + k) * 128 + (j - 128)];
        Wcat1[((size_t)m * 256 + j) * 128 + k] = (ushort)f2bf(v);
    } else {
        int j2 = j - 256;
        float v = (j2 < 64) ? W2l[((size_t)m * 128 + k) * 64 + j2]
                            : W2r[((size_t)m * 128 + k) * 64 + (j2 - 64)];
        Wcat2[((size_t)m * 128 + j2) * 128 + k] = (ushort)f2bf(v);
    }
}

// ============ MFMA GEMM1: t1 (fp8) and r1 (bf16, +b1) = x @ {W1l, W1r} ============
__global__ __launch_bounds__(256) void k_mfma1(
    const float* __restrict__ x, const ushort* __restrict__ Wcat1,
    const float* __restrict__ b1, uchar* __restrict__ t1, ushort* __restrict__ r1)
{
    const int m = blockIdx.y;
    const int row0 = blockIdx.x * 128;
    const int tid = threadIdx.x;
    const int lane = tid & 63, w = tid >> 6;
    const int wr = w >> 1, wc = w & 1;

    __shared__ ushort As[128][136];
    __shared__ ushort Bs[128][136];

    const float* Am = x + (size_t)m * Nn * 128;

    #pragma unroll
    for (int i = 0; i < 16; i++) {
        int f4 = tid + i * 256;
        int row = f4 >> 5, c4 = f4 & 31;
        int gr = row0 + row; if (gr >= Nn) gr = Nn - 1;
        float4 v = *(const float4*)(Am + (size_t)gr * 128 + c4 * 4);
        uint lo = f2bf(v.x) | (f2bf(v.y) << 16);
        uint hi = f2bf(v.z) | (f2bf(v.w) << 16);
        *(uint2*)&As[row][c4 * 4] = make_uint2(lo, hi);
    }

    for (int z = 0; z < 2; z++) {
        const ushort* Bm = Wcat1 + ((size_t)m * 256 + (size_t)z * 128) * 128;
        if (z) __syncthreads();
        #pragma unroll
        for (int i = 0; i < 8; i++) {
            int c8 = tid + i * 256;
            int row = c8 >> 4, c = c8 & 15;
            *(bf16x8*)&Bs[row][c * 8] = *(const bf16x8*)(Bm + (size_t)row * 128 + c * 8);
        }
        __syncthreads();

        f32x4 acc[4][4];
        #pragma unroll
        for (int i = 0; i < 4; i++)
            #pragma unroll
            for (int j = 0; j < 4; j++) acc[i][j] = (f32x4){0.f, 0.f, 0.f, 0.f};

        #pragma unroll
        for (int ks = 0; ks < 4; ks++) {
            bf16x8 a[4], b[4];
            #pragma unroll
            for (int i = 0; i < 4; i++)
                a[i] = *(const bf16x8*)&As[wr * 64 + i * 16 + (lane & 15)][ks * 32 + (lane >> 4) * 8];
            #pragma unroll
            for (int j = 0; j < 4; j++)
                b[j] = *(const bf16x8*)&Bs[wc * 64 + j * 16 + (lane & 15)][ks * 32 + (lane >> 4) * 8];
            #pragma unroll
            for (int i = 0; i < 4; i++)
                #pragma unroll
                for (int j = 0; j < 4; j++)
                    acc[i][j] = mfma16(a[i], b[j], acc[i][j]);
        }

        if (z == 0) {
            uchar* outp = t1 + (size_t)m * Nn * 128;
            #pragma unroll
            for (int j = 0; j < 4; j++) {
                int col = wc * 64 + j * 16 + (lane & 15);
                #pragma unroll
                for (int i = 0; i < 4; i++) {
                    #pragma unroll
                    for (int q = 0; q < 4; q++) {
                        int row = row0 + wr * 64 + i * 16 + (lane >> 4) * 4 + q;
                        if (row < Nn)
                            outp[(size_t)row * 128 + col] = f2fp8(acc[i][j][q]);
                    }
                }
            }
        } else {
            ushort* outp = r1 + (size_t)m * Nn * 128;
            #pragma unroll
            for (int j = 0; j < 4; j++) {
                int col = wc * 64 + j * 16 + (lane & 15);
                float bias = b1[m * 128 + col];
                #pragma unroll
                for (int i = 0; i < 4; i++) {
                    #pragma unroll
                    for (int q = 0; q < 4; q++) {
                        int row = row0 + wr * 64 + i * 16 + (lane >> 4) * 4 + q;
                        if (row < Nn)
                            outp[(size_t)row * 128 + col] = (ushort)f2bf(acc[i][j][q] + bias);
                    }
                }
            }
        }
    }
}

// ============ MFMA GEMM2: t2 (bf16) / r2 (bf16, +b2) = h @ Wcat2 ============
__global__ __launch_bounds__(256) void k_mfma2(
    const ushort* __restrict__ h, const ushort* __restrict__ Wcat2,
    const float* __restrict__ b2, ushort* __restrict__ t2, ushort* __restrict__ r2)
{
    const int m = blockIdx.y;
    const int row0 = blockIdx.x * 128;
    const int tid = threadIdx.x;
    const int lane = tid & 63, w = tid >> 6;
    const int wr = w >> 1, wc = w & 1;

    __shared__ ushort As[128][136];
    __shared__ ushort Bs[128][136];

    const ushort* Am = h + (size_t)m * Nn * 128;
    const ushort* Bm = Wcat2 + (size_t)m * 128 * 128;

    #pragma unroll
    for (int i = 0; i < 8; i++) {
        int c8 = tid + i * 256;
        int row = c8 >> 4, c = c8 & 15;
        int gr = row0 + row; if (gr >= Nn) gr = Nn - 1;
        *(bf16x8*)&As[row][c * 8] = *(const bf16x8*)(Am + (size_t)gr * 128 + c * 8);
    }
    #pragma unroll
    for (int i = 0; i < 8; i++) {
        int c8 = tid + i * 256;
        int row = c8 >> 4, c = c8 & 15;
        *(bf16x8*)&Bs[row][c * 8] = *(const bf16x8*)(Bm + (size_t)row * 128 + c * 8);
    }
    __syncthreads();

    f32x4 acc[4][4];
    #pragma unroll
    for (int i = 0; i < 4; i++)
        #pragma unroll
        for (int j = 0; j < 4; j++) acc[i][j] = (f32x4){0.f, 0.f, 0.f, 0.f};

    #pragma unroll
    for (int ks = 0; ks < 4; ks++) {
        bf16x8 a[4], b[4];
        #pragma unroll
        for (int i = 0; i < 4; i++)
            a[i] = *(const bf16x8*)&As[wr * 64 + i * 16 + (lane & 15)][ks * 32 + (lane >> 4) * 8];
        #pragma unroll
        for (int j = 0; j < 4; j++)
            b[j] = *(const bf16x8*)&Bs[wc * 64 + j * 16 + (lane & 15)][ks * 32 + (lane >> 4) * 8];
        #pragma unroll
        for (int i = 0; i < 4; i++)
            #pragma unroll
            for (int j = 0; j < 4; j++)
                acc[i][j] = mfma16(a[i], b[j], acc[i][j]);
    }

    ushort* outp = (wc ? r2 : t2) + (size_t)m * Nn * 64;
    #pragma unroll
    for (int j = 0; j < 4; j++) {
        int cl = j * 16 + (lane & 15);
        float bias = wc ? b2[m * 64 + cl] : 0.0f;
        #pragma unroll
        for (int i = 0; i < 4; i++) {
            #pragma unroll
            for (int q = 0; q < 4; q++) {
                int row = row0 + wr * 64 + i * 16 + (lane >> 4) * 4 + q;
                if (row < Nn)
                    outp[(size_t)row * 64 + cl] = (ushort)f2bf(acc[i][j][q] + bias);
            }
        }
    }
}

// ============ agg1: h = ELU(mean-gather(t1 fp8) + r1), bf16 out ============
__global__ __launch_bounds__(256) void k_agg_elu(
    const uchar* __restrict__ t1, const ushort* __restrict__ r1,
    const int* __restrict__ off, const int* __restrict__ cnt,
    const float* __restrict__ inv, const ushort* __restrict__ esrc,
    ushort* __restrict__ h)
{
    int lane = threadIdx.x & 63;
    int grp = lane >> 3;
    int sub = lane & 7;
    int node = ((blockIdx.x * 256 + threadIdx.x) >> 6) * 8 + grp;
    if (node >= METAc * Nn) return;
    int m = node / Nn, n = node - m * Nn;
    int start = off[m * Nn + n];
    int c = cnt[m * Nn + n];
    const ushort* es = esrc + (size_t)m * Ee + start;
    const uchar* tm = t1 + (size_t)m * Nn * 128;

    f32x2 a[8];
    #pragma unroll
    for (int k = 0; k < 8; k++) a[k] = (f32x2){0.f, 0.f};

    int e = 0;
    for (; e + 1 < c; e += 2) {
        int s0 = es[e], s1 = es[e + 1];
        uint4 v0 = *(const uint4*)(tm + (size_t)s0 * 128 + sub * 16);
        uint4 v1 = *(const uint4*)(tm + (size_t)s1 * 128 + sub * 16);
        a[0] += CVT8LO(v0.x); a[1] += CVT8HI(v0.x);
        a[2] += CVT8LO(v0.y); a[3] += CVT8HI(v0.y);
        a[4] += CVT8LO(v0.z); a[5] += CVT8HI(v0.z);
        a[6] += CVT8LO(v0.w); a[7] += CVT8HI(v0.w);
        a[0] += CVT8LO(v1.x); a[1] += CVT8HI(v1.x);
        a[2] += CVT8LO(v1.y); a[3] += CVT8HI(v1.y);
        a[4] += CVT8LO(v1.z); a[5] += CVT8HI(v1.z);
        a[6] += CVT8LO(v1.w); a[7] += CVT8HI(v1.w);
    }
    if (e < c) {
        int s0 = es[e];
        uint4 v0 = *(const uint4*)(tm + (size_t)s0 * 128 + sub * 16);
        a[0] += CVT8LO(v0.x); a[1] += CVT8HI(v0.x);
        a[2] += CVT8LO(v0.y); a[3] += CVT8HI(v0.y);
        a[4] += CVT8LO(v0.z); a[5] += CVT8HI(v0.z);
        a[6] += CVT8LO(v0.w); a[7] += CVT8HI(v0.w);
    }

    float iv = inv[m * Nn + n];
    const uint* rrow = (const uint*)(r1 + ((size_t)m * Nn + n) * 128);
    uint4 rv0 = *(const uint4*)(rrow + sub * 8);
    uint4 rv1 = *(const uint4*)(rrow + sub * 8 + 4);
    uint rw[8] = {rv0.x, rv0.y, rv0.z, rv0.w, rv1.x, rv1.y, rv1.z, rv1.w};
    uint o[8];
    #pragma unroll
    for (int k = 0; k < 8; k++) {
        float z0 = a[k].x * iv + bf2f(rw[k] & 0xffffu);
        float z1 = a[k].y * iv + bf2f(rw[k] >> 16);
        z0 = z0 > 0.0f ? z0 : (__expf(z0) - 1.0f);
        z1 = z1 > 0.0f ? z1 : (__expf(z1) - 1.0f);
        o[k] = f2bf(z0) | (f2bf(z1) << 16);
    }
    uint* hrow = (uint*)(h + ((size_t)m * Nn + n) * 128) + sub * 8;
    *(uint4*)hrow       = make_uint4(o[0], o[1], o[2], o[3]);
    *(uint4*)(hrow + 4) = make_uint4(o[4], o[5], o[6], o[7]);
}

// ============ agg2: out = log_softmax(mean-gather(t2 bf16) + r2) ============
__global__ __launch_bounds__(256) void k_agg_lsm(
    const ushort* __restrict__ t2, const ushort* __restrict__ r2,
    const int* __restrict__ off, const int* __restrict__ cnt,
    const float* __restrict__ inv, const ushort* __restrict__ esrc,
    float* __restrict__ out)
{
    int lane = threadIdx.x & 63;
    int grp = lane >> 3;
    int sub = lane & 7;
    int node = ((blockIdx.x * 256 + threadIdx.x) >> 6) * 8 + grp;
    if (node >= METAc * Nn) return;
    int m = node / Nn, n = node - m * Nn;
    int start = off[m * Nn + n];
    int c = cnt[m * Nn + n];
    const ushort* es = esrc + (size_t)m * Ee + start;
    const ushort* tm = t2 + (size_t)m * Nn * 64;

    f32x2 a[4];
    #pragma unroll
    for (int k = 0; k < 4; k++) a[k] = (f32x2){0.f, 0.f};

    int e = 0;
    for (; e + 1 < c; e += 2) {
        int s0 = es[e], s1 = es[e + 1];
        uint4 v0 = *(const uint4*)(tm + (size_t)s0 * 64 + sub * 8);
        uint4 v1 = *(const uint4*)(tm + (size_t)s1 * 64 + sub * 8);
        a[0] += up2(v0.x); a[1] += up2(v0.y); a[2] += up2(v0.z); a[3] += up2(v0.w);
        a[0] += up2(v1.x); a[1] += up2(v1.y); a[2] += up2(v1.z); a[3] += up2(v1.w);
    }
    if (e < c) {
        int s0 = es[e];
        uint4 v0 = *(const uint4*)(tm + (size_t)s0 * 64 + sub * 8);
        a[0] += up2(v0.x); a[1] += up2(v0.y); a[2] += up2(v0.z); a[3] += up2(v0.w);
    }

    float iv = inv[m * Nn + n];
    uint4 rv = *(const uint4*)(r2 + ((size_t)m * Nn + n) * 64 + sub * 8);
    uint rr[4] = {rv.x, rv.y, rv.z, rv.w};
    float z[8];
    #pragma unroll
    for (int k = 0; k < 4; k++) {
        z[2 * k]     = a[k].x * iv + bf2f(rr[k] & 0xffffu);
        z[2 * k + 1] = a[k].y * iv + bf2f(rr[k] >> 16);
    }
    float mx = z[0];
    #pragma unroll
    for (int k = 1; k < 8; k++) mx = fmaxf(mx, z[k]);
    #pragma unroll
    for (int o = 1; o <= 4; o <<= 1) mx = fmaxf(mx, __shfl_xor(mx, o));
    float s = 0.0f;
    #pragma unroll
    for (int k = 0; k < 8; k++) s += __expf(z[k] - mx);
    #pragma unroll
    for (int o = 1; o <= 4; o <<= 1) s += __shfl_xor(s, o);
    float lse = mx + __logf(s);
    float* op = out + ((size_t)m * Nn + n) * 64 + sub * 8;
    *(float4*)op       = make_float4(z[0] - lse, z[1] - lse, z[2] - lse, z[3] - lse);
    *(float4*)(op + 4) = make_float4(z[4] - lse, z[5] - lse, z[6] - lse, z[7] - lse);
}

extern "C" void kernel_launch(void* const* d_in, const int* in_sizes, int n_in,
                              void* d_out, int out_size, void* d_ws, size_t ws_size,
                              hipStream_t stream) {
    const float* meta_x = (const float*)d_in[0];
    const int*   ei     = (const int*)d_in[1];
    const float* W1l    = (const float*)d_in[2];
    const float* W1r    = (const float*)d_in[3];
    const float* b1     = (const float*)d_in[4];
    const float* W2l    = (const float*)d_in[5];
    const float* W2r    = (const float*)d_in[6];
    const float* b2     = (const float*)d_in[7];
    float* out = (float*)d_out;

    const size_t nN = (size_t)METAc * Nn;

    float* inv   = (float*)d_ws;                         // nN
    int*   cnt   = (int*)(inv + nN);                     // nN
    int*   off   = cnt + nN;                             // nN
    int*   ghist = off + nN;                             // METAc*NCHK*BKT
    int*   sofs  = ghist + (size_t)METAc * NCHK * BKT;   // METAc*BKT*NCHK
    int*   totals= sofs + (size_t)METAc * BKT * NCHK;    // METAc*BKT
    int*   bbase = totals + METAc * BKT;                 // METAc*BKT
    uint*  packed= (uint*)(bbase + METAc * BKT);         // METAc*Ee
    uint*  mid   = packed + (size_t)METAc * Ee;          // METAc*Ee
    ushort* esrc = (ushort*)(mid + (size_t)METAc * Ee);  // METAc*Ee
    uchar* t1    = (uchar*)(esrc + (size_t)METAc * Ee);  // nN*128 fp8
    ushort* r1   = (ushort*)(t1 + nN * 128);
    ushort* h    = r1 + nN * 128;
    ushort* t2   = h + nN * 128;                         // nN*64 bf16
    ushort* r2   = t2 + nN * 64;
    ushort* Wcat1 = r2 + nN * 64;
    ushort* Wcat2 = Wcat1 + (size_t)METAc * 256 * 128;

    k_packhist<<<METAc * NCHK, 256, 0, stream>>>(ei, packed, ghist);
    k_bscan<<<METAc * BKT, 1024, 0, stream>>>(ghist, sofs, totals);
    k_bbase<<<METAc, 256, 0, stream>>>(totals, bbase);
    k_scatterP<<<METAc * NCHK, 256, 0, stream>>>(packed, sofs, bbase, mid);
    k_binb<<<METAc * BKT, 256, 0, stream>>>(mid, bbase, off, cnt, inv, esrc);
    k_wcat<<<(METAc * 384 * 128 + 255) / 256, 256, 0, stream>>>(W1l, W1r, W2l, W2r, Wcat1, Wcat2);

    k_mfma1<<<dim3((Nn + 127) / 128, METAc), 256, 0, stream>>>(meta_x, Wcat1, b1, t1, r1);
    k_agg_elu<<<(METAc * Nn / 8 + 255) / 256 * 64, 256, 0, stream>>>(t1, r1, off, cnt, inv, esrc, h);
    k_mfma2<<<dim3((Nn + 127) / 128, METAc), 256, 0, stream>>>(h, Wcat2, b2, t2, r2);
    k_agg_lsm<<<(METAc * Nn / 8 + 255) / 256 * 64, 256, 0, stream>>>(t2, r2, off, cnt, inv, esrc, out);
}

// Round 20
// 218.251 us; speedup vs baseline: 2.8850x; 1.1655x over previous
//
#include <hip/hip_runtime.h>

#define METAc 3
#define Nn 50000
#define Ee 640000
#define BKT 200      // dst buckets per graph
#define BN 250       // nodes per bucket (200*250 = 50000 exact)
#define NCHK 625     // 1024-edge chunks per graph (625*1024 = 640000 exact)
#define SEGCAP 4608  // LDS edge cap per bucket (mean 3200, sigma 57 -> +24 sigma)

typedef unsigned int uint;
typedef unsigned short ushort;
typedef unsigned char uchar;
typedef __attribute__((ext_vector_type(8))) short bf16x8;
typedef __attribute__((ext_vector_type(4))) float f32x4;
typedef __attribute__((ext_vector_type(2))) float f32x2;
typedef __attribute__((ext_vector_type(4))) uint uint4v;

#define CVT8LO(w) ((f32x2)__builtin_amdgcn_cvt_pk_f32_fp8((w), false))
#define CVT8HI(w) ((f32x2)__builtin_amdgcn_cvt_pk_f32_fp8((w), true))

__device__ __forceinline__ float bf2f(uint u16) {
    union { uint u; float f; } v; v.u = u16 << 16; return v.f;
}
__device__ __forceinline__ uint f2bf(float f) {
    union { float f; uint u; } v; v.f = f;
    return (v.u + 0x7fffu + ((v.u >> 16) & 1u)) >> 16;
}
__device__ __forceinline__ uchar f2fp8(float f) {
    return (uchar)(__builtin_amdgcn_cvt_pk_fp8_f32(f, f, 0u, false) & 0xffu);
}
__device__ __forceinline__ f32x2 up2(uint u) {
    union { uint2 u2; f32x2 f; } cv;
    cv.u2.x = u << 16;
    cv.u2.y = u & 0xffff0000u;
    return cv.f;
}
__device__ __forceinline__ f32x4 mfma16(bf16x8 a, bf16x8 b, f32x4 c) {
    return __builtin_amdgcn_mfma_f32_16x16x32_bf16(a, b, c, 0, 0, 0);
}
__device__ __forceinline__ uint4v nt_load4(const void* p) {
    return __builtin_nontemporal_load((const uint4v*)p);
}

// ===== 1) pack + per-chunk bucket histogram (no global atomics) =====
__global__ __launch_bounds__(256) void k_packhist(const int* __restrict__ ei,
                                                  uint* __restrict__ packed,
                                                  int* __restrict__ ghist) {
    const int m = blockIdx.x / NCHK;
    const int b = blockIdx.x - m * NCHK;
    const int t = threadIdx.x;
    __shared__ int hist[BKT];
    if (t < BKT) hist[t] = 0;
    __syncthreads();

    const int e4 = b * 256 + t;                 // uint4 index within graph
    const int* base = ei + (size_t)m * 2 * Ee;
    uint4v d = nt_load4(base + Ee + e4 * 4);
    uint4v s = nt_load4(base + e4 * 4);
    uint4v p;
    p.x = (s.x & 0xffffu) | (d.x << 16);
    p.y = (s.y & 0xffffu) | (d.y << 16);
    p.z = (s.z & 0xffffu) | (d.z << 16);
    p.w = (s.w & 0xffffu) | (d.w << 16);
    *(uint4v*)(packed + (size_t)m * Ee + e4 * 4) = p;
    atomicAdd(&hist[(int)(d.x) / BN], 1);
    atomicAdd(&hist[(int)(d.y) / BN], 1);
    atomicAdd(&hist[(int)(d.z) / BN], 1);
    atomicAdd(&hist[(int)(d.w) / BN], 1);
    __syncthreads();
    if (t < BKT) ghist[((size_t)m * NCHK + b) * BKT + t] = hist[t];
}

// ===== 2) per-(m,bucket) exclusive scan over chunks -> sofs, totals =====
__global__ __launch_bounds__(1024) void k_bscan(const int* __restrict__ ghist,
                                                int* __restrict__ sofs,
                                                int* __restrict__ totals) {
    const int m = blockIdx.x / BKT;
    const int k = blockIdx.x - m * BKT;
    const int t = threadIdx.x;
    __shared__ int sc[1024];
    int v = (t < NCHK) ? ghist[((size_t)m * NCHK + t) * BKT + k] : 0;
    sc[t] = v;
    __syncthreads();
    for (int st = 1; st < 1024; st <<= 1) {
        int add = (t >= st) ? sc[t - st] : 0;
        __syncthreads();
        sc[t] += add;
        __syncthreads();
    }
    if (t < NCHK) sofs[((size_t)m * BKT + k) * NCHK + t] = sc[t] - v;
    if (t == NCHK - 1) totals[m * BKT + k] = sc[t];
}

// ===== 3) per-graph scan of bucket totals -> bucket bases =====
__global__ __launch_bounds__(256) void k_bbase(const int* __restrict__ totals,
                                               int* __restrict__ bbase) {
    const int m = blockIdx.x;
    const int t = threadIdx.x;
    __shared__ int sc[256];
    int v = (t < BKT) ? totals[m * BKT + t] : 0;
    sc[t] = v;
    __syncthreads();
    for (int st = 1; st < 256; st <<= 1) {
        int add = (t >= st) ? sc[t - st] : 0;
        __syncthreads();
        sc[t] += add;
        __syncthreads();
    }
    if (t < BKT) bbase[m * BKT + t] = sc[t] - v;
}

// ===== 4) bucket partition: packed -> mid (LDS cursors, no global atomics) =====
__global__ __launch_bounds__(256) void k_scatterP(const uint* __restrict__ packed,
                                                  const int* __restrict__ sofs,
                                                  const int* __restrict__ bbase,
                                                  uint* __restrict__ mid) {
    const int m = blockIdx.x / NCHK;
    const int b = blockIdx.x - m * NCHK;
    const int t = threadIdx.x;
    __shared__ int curs[BKT];
    if (t < BKT)
        curs[t] = bbase[m * BKT + t] + sofs[((size_t)m * BKT + t) * NCHK + b];
    __syncthreads();

    const int e4 = b * 256 + t;
    uint4v p = *(const uint4v*)(packed + (size_t)m * Ee + e4 * 4);
    uint* mm = mid + (size_t)m * Ee;
    int kk, pos;
    kk = (int)(p.x >> 16) / BN; pos = atomicAdd(&curs[kk], 1); mm[pos] = p.x;
    kk = (int)(p.y >> 16) / BN; pos = atomicAdd(&curs[kk], 1); mm[pos] = p.y;
    kk = (int)(p.z >> 16) / BN; pos = atomicAdd(&curs[kk], 1); mm[pos] = p.z;
    kk = (int)(p.w >> 16) / BN; pos = atomicAdd(&curs[kk], 1); mm[pos] = p.w;
}

// ===== 5) per-bucket bin: mid -> esrc (coalesced), also off/cnt/inv =====
__global__ __launch_bounds__(256) void k_binb(const uint* __restrict__ mid,
                                              const int* __restrict__ bbase,
                                              int* __restrict__ off,
                                              int* __restrict__ cnt,
                                              float* __restrict__ inv,
                                              ushort* __restrict__ esrc) {
    const int m = blockIdx.x / BKT;
    const int k = blockIdx.x - m * BKT;
    const int t = threadIdx.x;
    const int n0 = k * BN;
    const int sbase = bbase[m * BKT + k];
    const int send = (k < BKT - 1) ? bbase[m * BKT + k + 1] : Ee;
    const int seglen = send - sbase;

    __shared__ uint seg[SEGCAP];
    __shared__ ushort outs[SEGCAP];
    __shared__ int lcnt[BN];
    __shared__ int lcur[BN];
    __shared__ int sc[256];

    const uint* mm = mid + (size_t)m * Ee + sbase;
    ushort* em = esrc + (size_t)m * Ee + sbase;
    const bool fits = seglen <= SEGCAP;

    if (fits)
        for (int i = t; i < seglen; i += 256) seg[i] = mm[i];
    if (t < BN) lcnt[t] = 0;
    __syncthreads();

    for (int i = t; i < seglen; i += 256) {
        uint p = fits ? seg[i] : mm[i];
        atomicAdd(&lcnt[(int)(p >> 16) - n0], 1);
    }
    __syncthreads();

    int v = (t < BN) ? lcnt[t] : 0;
    sc[t] = v;
    __syncthreads();
    for (int st = 1; st < 256; st <<= 1) {
        int add = (t >= st) ? sc[t - st] : 0;
        __syncthreads();
        sc[t] += add;
        __syncthreads();
    }
    if (t < BN) {
        int excl = sc[t] - v;
        lcur[t] = excl;
        int node = m * Nn + n0 + t;
        off[node] = sbase + excl;
        cnt[node] = v;
        inv[node] = 1.0f / fmaxf((float)v, 1.0f);
    }
    __syncthreads();

    if (fits) {
        for (int i = t; i < seglen; i += 256) {
            uint p = seg[i];
            int pos = atomicAdd(&lcur[(int)(p >> 16) - n0], 1);
            outs[pos] = (ushort)(p & 0xffffu);
        }
        __syncthreads();
        for (int i = t; i < seglen; i += 256) em[i] = outs[i];
    } else {
        for (int i = t; i < seglen; i += 256) {
            uint p = mm[i];
            int pos = atomicAdd(&lcur[(int)(p >> 16) - n0], 1);
            em[pos] = (ushort)(p & 0xffffu);
        }
    }
}

// ============ weight prep ============
__global__ __launch_bounds__(256) void k_wcat(
    const float* __restrict__ W1l, const float* __restrict__ W1r,
    const float* __restrict__ W2l, const float* __restrict__ W2r,
    ushort* __restrict__ Wcat1, ushort* __restrict__ Wcat2)
{
    int idx = blockIdx.x * 256 + threadIdx.x;
    if (idx >= METAc * 384 * 128) return;
    int m = idx / (384 * 128);
    int rem = idx - m * 384 * 128;
    int j = rem >> 7;
    int k = rem & 127;
    if (j < 256) {
        float v = (j < 128) ? W1l[((size_t)m * 128 + k) * 128 + j]
                            : W1r[((size_t)m * 128 + k) * 128 + (j - 128)];
        Wcat1[((size_t)m * 256 + j) * 128 + k] = (ushort)f2bf(v);
    } else {
        int j2 = j - 256;
        float v = (j2 < 64) ? W2l[((size_t)m * 128 + k) * 64 + j2]
                            : W2r[((size_t)m * 128 + k) * 64 + (j2 - 64)];
        Wcat2[((size_t)m * 128 + j2) * 128 + k] = (ushort)f2bf(v);
    }
}

// ============ MFMA GEMM1: t1 (fp8) and r1 (bf16, +b1) = x @ {W1l, W1r} ============
// Epilogue staged through Bs (free after MFMA) -> fully coalesced uint4 stores.
__global__ __launch_bounds__(256) void k_mfma1(
    const float* __restrict__ x, const ushort* __restrict__ Wcat1,
    const float* __restrict__ b1, uchar* __restrict__ t1, ushort* __restrict__ r1)
{
    const int m = blockIdx.y;
    const int row0 = blockIdx.x * 128;
    const int tid = threadIdx.x;
    const int lane = tid & 63, w = tid >> 6;
    const int wr = w >> 1, wc = w & 1;

    __shared__ ushort As[128][136];
    __shared__ ushort Bs[128][136];

    const float* Am = x + (size_t)m * Nn * 128;

    #pragma unroll
    for (int i = 0; i < 16; i++) {
        int f4 = tid + i * 256;
        int row = f4 >> 5, c4 = f4 & 31;
        int gr = row0 + row; if (gr >= Nn) gr = Nn - 1;
        float4 v = *(const float4*)(Am + (size_t)gr * 128 + c4 * 4);
        uint lo = f2bf(v.x) | (f2bf(v.y) << 16);
        uint hi = f2bf(v.z) | (f2bf(v.w) << 16);
        *(uint2*)&As[row][c4 * 4] = make_uint2(lo, hi);
    }

    for (int z = 0; z < 2; z++) {
        const ushort* Bm = Wcat1 + ((size_t)m * 256 + (size_t)z * 128) * 128;
        if (z) __syncthreads();   // flush reads done before overwriting Bs
        #pragma unroll
        for (int i = 0; i < 8; i++) {
            int c8 = tid + i * 256;
            int row = c8 >> 4, c = c8 & 15;
            *(bf16x8*)&Bs[row][c * 8] = *(const bf16x8*)(Bm + (size_t)row * 128 + c * 8);
        }
        __syncthreads();

        f32x4 acc[4][4];
        #pragma unroll
        for (int i = 0; i < 4; i++)
            #pragma unroll
            for (int j = 0; j < 4; j++) acc[i][j] = (f32x4){0.f, 0.f, 0.f, 0.f};

        #pragma unroll
        for (int ks = 0; ks < 4; ks++) {
            bf16x8 a[4], b[4];
            #pragma unroll
            for (int i = 0; i < 4; i++)
                a[i] = *(const bf16x8*)&As[wr * 64 + i * 16 + (lane & 15)][ks * 32 + (lane >> 4) * 8];
            #pragma unroll
            for (int j = 0; j < 4; j++)
                b[j] = *(const bf16x8*)&Bs[wc * 64 + j * 16 + (lane & 15)][ks * 32 + (lane >> 4) * 8];
            #pragma unroll
            for (int i = 0; i < 4; i++)
                #pragma unroll
                for (int j = 0; j < 4; j++)
                    acc[i][j] = mfma16(a[i], b[j], acc[i][j]);
        }

        __syncthreads();   // all Bs fragment reads complete -> reuse Bs as staging
        if (z == 0) {
            uchar* stg = (uchar*)&Bs[0][0];   // 128x128 fp8 = 16KB
            #pragma unroll
            for (int j = 0; j < 4; j++) {
                int col = wc * 64 + j * 16 + (lane & 15);
                #pragma unroll
                for (int i = 0; i < 4; i++) {
                    #pragma unroll
                    for (int q = 0; q < 4; q++) {
                        int row = wr * 64 + i * 16 + (lane >> 4) * 4 + q;
                        stg[row * 128 + col] = f2fp8(acc[i][j][q]);
                    }
                }
            }
            __syncthreads();
            uchar* outp = t1 + (size_t)m * Nn * 128 + (size_t)row0 * 128;
            #pragma unroll
            for (int i = 0; i < 4; i++) {
                int o = (tid + i * 256) * 16;
                if (row0 + (o >> 7) < Nn)
                    *(uint4*)(outp + o) = *(const uint4*)(stg + o);
            }
        } else {
            ushort* stg = &Bs[0][0];   // 128x128 bf16 = 32KB (Bs = 34.8KB)
            #pragma unroll
            for (int j = 0; j < 4; j++) {
                int col = wc * 64 + j * 16 + (lane & 15);
                float bias = b1[m * 128 + col];
                #pragma unroll
                for (int i = 0; i < 4; i++) {
                    #pragma unroll
                    for (int q = 0; q < 4; q++) {
                        int row = wr * 64 + i * 16 + (lane >> 4) * 4 + q;
                        stg[row * 128 + col] = (ushort)f2bf(acc[i][j][q] + bias);
                    }
                }
            }
            __syncthreads();
            ushort* outp = r1 + (size_t)m * Nn * 128 + (size_t)row0 * 128;
            #pragma unroll
            for (int i = 0; i < 8; i++) {
                int o = (tid + i * 256) * 8;   // ushort units, 16B granule
                if (row0 + (o >> 7) < Nn)
                    *(uint4*)(outp + o) = *(const uint4*)(stg + o);
            }
        }
    }
}

// ============ MFMA GEMM2: t2 (bf16) / r2 (bf16, +b2) = h @ Wcat2 ============
// Staged epilogue: t2 tile in Bs[0..8K), r2 tile in Bs[8K..16K) (ushort units).
__global__ __launch_bounds__(256) void k_mfma2(
    const ushort* __restrict__ h, const ushort* __restrict__ Wcat2,
    const float* __restrict__ b2, ushort* __restrict__ t2, ushort* __restrict__ r2)
{
    const int m = blockIdx.y;
    const int row0 = blockIdx.x * 128;
    const int tid = threadIdx.x;
    const int lane = tid & 63, w = tid >> 6;
    const int wr = w >> 1, wc = w & 1;

    __shared__ ushort As[128][136];
    __shared__ ushort Bs[128][136];

    const ushort* Am = h + (size_t)m * Nn * 128;
    const ushort* Bm = Wcat2 + (size_t)m * 128 * 128;

    #pragma unroll
    for (int i = 0; i < 8; i++) {
        int c8 = tid + i * 256;
        int row = c8 >> 4, c = c8 & 15;
        int gr = row0 + row; if (gr >= Nn) gr = Nn - 1;
        *(bf16x8*)&As[row][c * 8] = *(const bf16x8*)(Am + (size_t)gr * 128 + c * 8);
    }
    #pragma unroll
    for (int i = 0; i < 8; i++) {
        int c8 = tid + i * 256;
        int row = c8 >> 4, c = c8 & 15;
        *(bf16x8*)&Bs[row][c * 8] = *(const bf16x8*)(Bm + (size_t)row * 128 + c * 8);
    }
    __syncthreads();

    f32x4 acc[4][4];
    #pragma unroll
    for (int i = 0; i < 4; i++)
        #pragma unroll
        for (int j = 0; j < 4; j++) acc[i][j] = (f32x4){0.f, 0.f, 0.f, 0.f};

    #pragma unroll
    for (int ks = 0; ks < 4; ks++) {
        bf16x8 a[4], b[4];
        #pragma unroll
        for (int i = 0; i < 4; i++)
            a[i] = *(const bf16x8*)&As[wr * 64 + i * 16 + (lane & 15)][ks * 32 + (lane >> 4) * 8];
        #pragma unroll
        for (int j = 0; j < 4; j++)
            b[j] = *(const bf16x8*)&Bs[wc * 64 + j * 16 + (lane & 15)][ks * 32 + (lane >> 4) * 8];
        #pragma unroll
        for (int i = 0; i < 4; i++)
            #pragma unroll
            for (int j = 0; j < 4; j++)
                acc[i][j] = mfma16(a[i], b[j], acc[i][j]);
    }

    __syncthreads();   // Bs free -> staging
    ushort* stg = &Bs[0][0];
    ushort* my = stg + (wc ? 8192 : 0);   // 128x64 ushort tiles
    #pragma unroll
    for (int j = 0; j < 4; j++) {
        int cl = j * 16 + (lane & 15);
        float bias = wc ? b2[m * 64 + cl] : 0.0f;
        #pragma unroll
        for (int i = 0; i < 4; i++) {
            #pragma unroll
            for (int q = 0; q < 4; q++) {
                int row = wr * 64 + i * 16 + (lane >> 4) * 4 + q;
                my[row * 64 + cl] = (ushort)f2bf(acc[i][j][q] + bias);
            }
        }
    }
    __syncthreads();
    ushort* ot = t2 + (size_t)m * Nn * 64 + (size_t)row0 * 64;
    ushort* orr = r2 + (size_t)m * Nn * 64 + (size_t)row0 * 64;
    #pragma unroll
    for (int i = 0; i < 4; i++) {
        int o = (tid + i * 256) * 8;   // ushort units
        if (row0 + (o >> 6) < Nn) {
            *(uint4*)(ot + o)  = *(const uint4*)(stg + o);
            *(uint4*)(orr + o) = *(const uint4*)(stg + 8192 + o);
        }
    }
}

// ============ agg1: h = ELU(mean-gather(t1 fp8) + r1), bf16 out ============
__global__ __launch_bounds__(256) void k_agg_elu(
    const uchar* __restrict__ t1, const ushort* __restrict__ r1,
    const int* __restrict__ off, const int* __restrict__ cnt,
    const float* __restrict__ inv, const ushort* __restrict__ esrc,
    ushort* __restrict__ h)
{
    int lane = threadIdx.x & 63;
    int grp = lane >> 3;
    int sub = lane & 7;
    int node = ((blockIdx.x * 256 + threadIdx.x) >> 6) * 8 + grp;
    if (node >= METAc * Nn) return;
    int m = node / Nn, n = node - m * Nn;
    int start = off[m * Nn + n];
    int c = cnt[m * Nn + n];
    const ushort* es = esrc + (size_t)m * Ee + start;
    const uchar* tm = t1 + (size_t)m * Nn * 128;

    f32x2 a[8];
    #pragma unroll
    for (int k = 0; k < 8; k++) a[k] = (f32x2){0.f, 0.f};

    int e = 0;
    for (; e + 1 < c; e += 2) {
        int s0 = es[e], s1 = es[e + 1];
        uint4 v0 = *(const uint4*)(tm + (size_t)s0 * 128 + sub * 16);
        uint4 v1 = *(const uint4*)(tm + (size_t)s1 * 128 + sub * 16);
        a[0] += CVT8LO(v0.x); a[1] += CVT8HI(v0.x);
        a[2] += CVT8LO(v0.y); a[3] += CVT8HI(v0.y);
        a[4] += CVT8LO(v0.z); a[5] += CVT8HI(v0.z);
        a[6] += CVT8LO(v0.w); a[7] += CVT8HI(v0.w);
        a[0] += CVT8LO(v1.x); a[1] += CVT8HI(v1.x);
        a[2] += CVT8LO(v1.y); a[3] += CVT8HI(v1.y);
        a[4] += CVT8LO(v1.z); a[5] += CVT8HI(v1.z);
        a[6] += CVT8LO(v1.w); a[7] += CVT8HI(v1.w);
    }
    if (e < c) {
        int s0 = es[e];
        uint4 v0 = *(const uint4*)(tm + (size_t)s0 * 128 + sub * 16);
        a[0] += CVT8LO(v0.x); a[1] += CVT8HI(v0.x);
        a[2] += CVT8LO(v0.y); a[3] += CVT8HI(v0.y);
        a[4] += CVT8LO(v0.z); a[5] += CVT8HI(v0.z);
        a[6] += CVT8LO(v0.w); a[7] += CVT8HI(v0.w);
    }

    float iv = inv[m * Nn + n];
    const uint* rrow = (const uint*)(r1 + ((size_t)m * Nn + n) * 128);
    uint4 rv0 = *(const uint4*)(rrow + sub * 8);
    uint4 rv1 = *(const uint4*)(rrow + sub * 8 + 4);
    uint rw[8] = {rv0.x, rv0.y, rv0.z, rv0.w, rv1.x, rv1.y, rv1.z, rv1.w};
    uint o[8];
    #pragma unroll
    for (int k = 0; k < 8; k++) {
        float z0 = a[k].x * iv + bf2f(rw[k] & 0xffffu);
        float z1 = a[k].y * iv + bf2f(rw[k] >> 16);
        z0 = z0 > 0.0f ? z0 : (__expf(z0) - 1.0f);
        z1 = z1 > 0.0f ? z1 : (__expf(z1) - 1.0f);
        o[k] = f2bf(z0) | (f2bf(z1) << 16);
    }
    uint* hrow = (uint*)(h + ((size_t)m * Nn + n) * 128) + sub * 8;
    *(uint4*)hrow       = make_uint4(o[0], o[1], o[2], o[3]);
    *(uint4*)(hrow + 4) = make_uint4(o[4], o[5], o[6], o[7]);
}

// ============ agg2: out = log_softmax(mean-gather(t2 bf16) + r2) ============
__global__ __launch_bounds__(256) void k_agg_lsm(
    const ushort* __restrict__ t2, const ushort* __restrict__ r2,
    const int* __restrict__ off, const int* __restrict__ cnt,
    const float* __restrict__ inv, const ushort* __restrict__ esrc,
    float* __restrict__ out)
{
    int lane = threadIdx.x & 63;
    int grp = lane >> 3;
    int sub = lane & 7;
    int node = ((blockIdx.x * 256 + threadIdx.x) >> 6) * 8 + grp;
    if (node >= METAc * Nn) return;
    int m = node / Nn, n = node - m * Nn;
    int start = off[m * Nn + n];
    int c = cnt[m * Nn + n];
    const ushort* es = esrc + (size_t)m * Ee + start;
    const ushort* tm = t2 + (size_t)m * Nn * 64;

    f32x2 a[4];
    #pragma unroll
    for (int k = 0; k < 4; k++) a[k] = (f32x2){0.f, 0.f};

    int e = 0;
    for (; e + 1 < c; e += 2) {
        int s0 = es[e], s1 = es[e + 1];
        uint4 v0 = *(const uint4*)(tm + (size_t)s0 * 64 + sub * 8);
        uint4 v1 = *(const uint4*)(tm + (size_t)s1 * 64 + sub * 8);
        a[0] += up2(v0.x); a[1] += up2(v0.y); a[2] += up2(v0.z); a[3] += up2(v0.w);
        a[0] += up2(v1.x); a[1] += up2(v1.y); a[2] += up2(v1.z); a[3] += up2(v1.w);
    }
    if (e < c) {
        int s0 = es[e];
        uint4 v0 = *(const uint4*)(tm + (size_t)s0 * 64 + sub * 8);
        a[0] += up2(v0.x); a[1] += up2(v0.y); a[2] += up2(v0.z); a[3] += up2(v0.w);
    }

    float iv = inv[m * Nn + n];
    uint4 rv = *(const uint4*)(r2 + ((size_t)m * Nn + n) * 64 + sub * 8);
    uint rr[4] = {rv.x, rv.y, rv.z, rv.w};
    float z[8];
    #pragma unroll
    for (int k = 0; k < 4; k++) {
        z[2 * k]     = a[k].x * iv + bf2f(rr[k] & 0xffffu);
        z[2 * k + 1] = a[k].y * iv + bf2f(rr[k] >> 16);
    }
    float mx = z[0];
    #pragma unroll
    for (int k = 1; k < 8; k++) mx = fmaxf(mx, z[k]);
    #pragma unroll
    for (int o = 1; o <= 4; o <<= 1) mx = fmaxf(mx, __shfl_xor(mx, o));
    float s = 0.0f;
    #pragma unroll
    for (int k = 0; k < 8; k++) s += __expf(z[k] - mx);
    #pragma unroll
    for (int o = 1; o <= 4; o <<= 1) s += __shfl_xor(s, o);
    float lse = mx + __logf(s);
    float* op = out + ((size_t)m * Nn + n) * 64 + sub * 8;
    *(float4*)op       = make_float4(z[0] - lse, z[1] - lse, z[2] - lse, z[3] - lse);
    *(float4*)(op + 4) = make_float4(z[4] - lse, z[5] - lse, z[6] - lse, z[7] - lse);
}

extern "C" void kernel_launch(void* const* d_in, const int* in_sizes, int n_in,
                              void* d_out, int out_size, void* d_ws, size_t ws_size,
                              hipStream_t stream) {
    const float* meta_x = (const float*)d_in[0];
    const int*   ei     = (const int*)d_in[1];
    const float* W1l    = (const float*)d_in[2];
    const float* W1r    = (const float*)d_in[3];
    const float* b1     = (const float*)d_in[4];
    const float* W2l    = (const float*)d_in[5];
    const float* W2r    = (const float*)d_in[6];
    const float* b2     = (const float*)d_in[7];
    float* out = (float*)d_out;

    const size_t nN = (size_t)METAc * Nn;

    float* inv   = (float*)d_ws;                         // nN
    int*   cnt   = (int*)(inv + nN);                     // nN
    int*   off   = cnt + nN;                             // nN
    int*   ghist = off + nN;                             // METAc*NCHK*BKT
    int*   sofs  = ghist + (size_t)METAc * NCHK * BKT;   // METAc*BKT*NCHK
    int*   totals= sofs + (size_t)METAc * BKT * NCHK;    // METAc*BKT
    int*   bbase = totals + METAc * BKT;                 // METAc*BKT
    uint*  packed= (uint*)(bbase + METAc * BKT);         // METAc*Ee
    uint*  mid   = packed + (size_t)METAc * Ee;          // METAc*Ee
    ushort* esrc = (ushort*)(mid + (size_t)METAc * Ee);  // METAc*Ee
    uchar* t1    = (uchar*)(esrc + (size_t)METAc * Ee);  // nN*128 fp8
    ushort* r1   = (ushort*)(t1 + nN * 128);
    ushort* h    = r1 + nN * 128;
    ushort* t2   = h + nN * 128;                         // nN*64 bf16
    ushort* r2   = t2 + nN * 64;
    ushort* Wcat1 = r2 + nN * 64;
    ushort* Wcat2 = Wcat1 + (size_t)METAc * 256 * 128;

    k_packhist<<<METAc * NCHK, 256, 0, stream>>>(ei, packed, ghist);
    k_bscan<<<METAc * BKT, 1024, 0, stream>>>(ghist, sofs, totals);
    k_bbase<<<METAc, 256, 0, stream>>>(totals, bbase);
    k_scatterP<<<METAc * NCHK, 256, 0, stream>>>(packed, sofs, bbase, mid);
    k_binb<<<METAc * BKT, 256, 0, stream>>>(mid, bbase, off, cnt, inv, esrc);
    k_wcat<<<(METAc * 384 * 128 + 255) / 256, 256, 0, stream>>>(W1l, W1r, W2l, W2r, Wcat1, Wcat2);

    k_mfma1<<<dim3((Nn + 127) / 128, METAc), 256, 0, stream>>>(meta_x, Wcat1, b1, t1, r1);
    k_agg_elu<<<(METAc * Nn / 8 + 255) / 256 * 64, 256, 0, stream>>>(t1, r1, off, cnt, inv, esrc, h);
    k_mfma2<<<dim3((Nn + 127) / 128, METAc), 256, 0, stream>>>(h, Wcat2, b2, t2, r2);
    k_agg_lsm<<<(METAc * Nn / 8 + 255) / 256 * 64, 256, 0, stream>>>(t2, r2, off, cnt, inv, esrc, out);
}

// Round 21
// 207.422 us; speedup vs baseline: 3.0356x; 1.0522x over previous
//
#include <hip/hip_runtime.h>

#define METAc 3
#define Nn 50000
#define Ee 640000
#define BKT 200      // dst buckets per graph
#define BN 250       // nodes per bucket (200*250 = 50000 exact)
#define NCHK 625     // 1024-edge chunks per graph (625*1024 = 640000 exact)
#define SEGCAP 4608  // LDS edge cap per bucket (mean 3200, sigma 57 -> +24 sigma)

typedef unsigned int uint;
typedef unsigned short ushort;
typedef unsigned char uchar;
typedef __attribute__((ext_vector_type(8))) short bf16x8;
typedef __attribute__((ext_vector_type(4))) float f32x4;
typedef __attribute__((ext_vector_type(2))) float f32x2;
typedef __attribute__((ext_vector_type(4))) uint uint4v;

#define CVT8LO(w) ((f32x2)__builtin_amdgcn_cvt_pk_f32_fp8((w), false))
#define CVT8HI(w) ((f32x2)__builtin_amdgcn_cvt_pk_f32_fp8((w), true))

__device__ __forceinline__ float bf2f(uint u16) {
    union { uint u; float f; } v; v.u = u16 << 16; return v.f;
}
__device__ __forceinline__ uint f2bf(float f) {
    union { float f; uint u; } v; v.f = f;
    return (v.u + 0x7fffu + ((v.u >> 16) & 1u)) >> 16;
}
__device__ __forceinline__ uchar f2fp8(float f) {
    return (uchar)(__builtin_amdgcn_cvt_pk_fp8_f32(f, f, 0u, false) & 0xffu);
}
__device__ __forceinline__ f32x2 up2(uint u) {
    union { uint2 u2; f32x2 f; } cv;
    cv.u2.x = u << 16;
    cv.u2.y = u & 0xffff0000u;
    return cv.f;
}
__device__ __forceinline__ f32x4 mfma16(bf16x8 a, bf16x8 b, f32x4 c) {
    return __builtin_amdgcn_mfma_f32_16x16x32_bf16(a, b, c, 0, 0, 0);
}
__device__ __forceinline__ uint4v nt_load4(const void* p) {
    return __builtin_nontemporal_load((const uint4v*)p);
}

// ===== 1) pack + per-chunk bucket histogram (no global atomics) =====
__global__ __launch_bounds__(256) void k_packhist(const int* __restrict__ ei,
                                                  uint* __restrict__ packed,
                                                  int* __restrict__ ghist) {
    const int m = blockIdx.x / NCHK;
    const int b = blockIdx.x - m * NCHK;
    const int t = threadIdx.x;
    __shared__ int hist[BKT];
    if (t < BKT) hist[t] = 0;
    __syncthreads();

    const int e4 = b * 256 + t;                 // uint4 index within graph
    const int* base = ei + (size_t)m * 2 * Ee;
    uint4v d = nt_load4(base + Ee + e4 * 4);
    uint4v s = nt_load4(base + e4 * 4);
    uint4v p;
    p.x = (s.x & 0xffffu) | (d.x << 16);
    p.y = (s.y & 0xffffu) | (d.y << 16);
    p.z = (s.z & 0xffffu) | (d.z << 16);
    p.w = (s.w & 0xffffu) | (d.w << 16);
    *(uint4v*)(packed + (size_t)m * Ee + e4 * 4) = p;
    atomicAdd(&hist[(int)(d.x) / BN], 1);
    atomicAdd(&hist[(int)(d.y) / BN], 1);
    atomicAdd(&hist[(int)(d.z) / BN], 1);
    atomicAdd(&hist[(int)(d.w) / BN], 1);
    __syncthreads();
    if (t < BKT) ghist[((size_t)m * NCHK + b) * BKT + t] = hist[t];
}

// ===== 2) per-(m,bucket) exclusive scan over chunks -> sofs, totals =====
__global__ __launch_bounds__(1024) void k_bscan(const int* __restrict__ ghist,
                                                int* __restrict__ sofs,
                                                int* __restrict__ totals) {
    const int m = blockIdx.x / BKT;
    const int k = blockIdx.x - m * BKT;
    const int t = threadIdx.x;
    __shared__ int sc[1024];
    int v = (t < NCHK) ? ghist[((size_t)m * NCHK + t) * BKT + k] : 0;
    sc[t] = v;
    __syncthreads();
    for (int st = 1; st < 1024; st <<= 1) {
        int add = (t >= st) ? sc[t - st] : 0;
        __syncthreads();
        sc[t] += add;
        __syncthreads();
    }
    if (t < NCHK) sofs[((size_t)m * BKT + k) * NCHK + t] = sc[t] - v;
    if (t == NCHK - 1) totals[m * BKT + k] = sc[t];
}

// ===== 3) per-graph scan of bucket totals -> bucket bases =====
__global__ __launch_bounds__(256) void k_bbase(const int* __restrict__ totals,
                                               int* __restrict__ bbase) {
    const int m = blockIdx.x;
    const int t = threadIdx.x;
    __shared__ int sc[256];
    int v = (t < BKT) ? totals[m * BKT + t] : 0;
    sc[t] = v;
    __syncthreads();
    for (int st = 1; st < 256; st <<= 1) {
        int add = (t >= st) ? sc[t - st] : 0;
        __syncthreads();
        sc[t] += add;
        __syncthreads();
    }
    if (t < BKT) bbase[m * BKT + t] = sc[t] - v;
}

// ===== 4) bucket partition: packed -> mid (LDS cursors, no global atomics) =====
__global__ __launch_bounds__(256) void k_scatterP(const uint* __restrict__ packed,
                                                  const int* __restrict__ sofs,
                                                  const int* __restrict__ bbase,
                                                  uint* __restrict__ mid) {
    const int m = blockIdx.x / NCHK;
    const int b = blockIdx.x - m * NCHK;
    const int t = threadIdx.x;
    __shared__ int curs[BKT];
    if (t < BKT)
        curs[t] = bbase[m * BKT + t] + sofs[((size_t)m * BKT + t) * NCHK + b];
    __syncthreads();

    const int e4 = b * 256 + t;
    uint4v p = *(const uint4v*)(packed + (size_t)m * Ee + e4 * 4);
    uint* mm = mid + (size_t)m * Ee;
    int kk, pos;
    kk = (int)(p.x >> 16) / BN; pos = atomicAdd(&curs[kk], 1); mm[pos] = p.x;
    kk = (int)(p.y >> 16) / BN; pos = atomicAdd(&curs[kk], 1); mm[pos] = p.y;
    kk = (int)(p.z >> 16) / BN; pos = atomicAdd(&curs[kk], 1); mm[pos] = p.z;
    kk = (int)(p.w >> 16) / BN; pos = atomicAdd(&curs[kk], 1); mm[pos] = p.w;
}

// ===== 5) per-bucket bin: mid -> esrc (coalesced), also off/cnt/inv =====
__global__ __launch_bounds__(256) void k_binb(const uint* __restrict__ mid,
                                              const int* __restrict__ bbase,
                                              int* __restrict__ off,
                                              int* __restrict__ cnt,
                                              float* __restrict__ inv,
                                              ushort* __restrict__ esrc) {
    const int m = blockIdx.x / BKT;
    const int k = blockIdx.x - m * BKT;
    const int t = threadIdx.x;
    const int n0 = k * BN;
    const int sbase = bbase[m * BKT + k];
    const int send = (k < BKT - 1) ? bbase[m * BKT + k + 1] : Ee;
    const int seglen = send - sbase;

    __shared__ uint seg[SEGCAP];
    __shared__ ushort outs[SEGCAP];
    __shared__ int lcnt[BN];
    __shared__ int lcur[BN];
    __shared__ int sc[256];

    const uint* mm = mid + (size_t)m * Ee + sbase;
    ushort* em = esrc + (size_t)m * Ee + sbase;
    const bool fits = seglen <= SEGCAP;

    if (fits)
        for (int i = t; i < seglen; i += 256) seg[i] = mm[i];
    if (t < BN) lcnt[t] = 0;
    __syncthreads();

    for (int i = t; i < seglen; i += 256) {
        uint p = fits ? seg[i] : mm[i];
        atomicAdd(&lcnt[(int)(p >> 16) - n0], 1);
    }
    __syncthreads();

    int v = (t < BN) ? lcnt[t] : 0;
    sc[t] = v;
    __syncthreads();
    for (int st = 1; st < 256; st <<= 1) {
        int add = (t >= st) ? sc[t - st] : 0;
        __syncthreads();
        sc[t] += add;
        __syncthreads();
    }
    if (t < BN) {
        int excl = sc[t] - v;
        lcur[t] = excl;
        int node = m * Nn + n0 + t;
        off[node] = sbase + excl;
        cnt[node] = v;
        inv[node] = 1.0f / fmaxf((float)v, 1.0f);
    }
    __syncthreads();

    if (fits) {
        for (int i = t; i < seglen; i += 256) {
            uint p = seg[i];
            int pos = atomicAdd(&lcur[(int)(p >> 16) - n0], 1);
            outs[pos] = (ushort)(p & 0xffffu);
        }
        __syncthreads();
        for (int i = t; i < seglen; i += 256) em[i] = outs[i];
    } else {
        for (int i = t; i < seglen; i += 256) {
            uint p = mm[i];
            int pos = atomicAdd(&lcur[(int)(p >> 16) - n0], 1);
            em[pos] = (ushort)(p & 0xffffu);
        }
    }
}

// ============ weight prep ============
__global__ __launch_bounds__(256) void k_wcat(
    const float* __restrict__ W1l, const float* __restrict__ W1r,
    const float* __restrict__ W2l, const float* __restrict__ W2r,
    ushort* __restrict__ Wcat1, ushort* __restrict__ Wcat2)
{
    int idx = blockIdx.x * 256 + threadIdx.x;
    if (idx >= METAc * 384 * 128) return;
    int m = idx / (384 * 128);
    int rem = idx - m * 384 * 128;
    int j = rem >> 7;
    int k = rem & 127;
    if (j < 256) {
        float v = (j < 128) ? W1l[((size_t)m * 128 + k) * 128 + j]
                            : W1r[((size_t)m * 128 + k) * 128 + (j - 128)];
        Wcat1[((size_t)m * 256 + j) * 128 + k] = (ushort)f2bf(v);
    } else {
        int j2 = j - 256;
        float v = (j2 < 64) ? W2l[((size_t)m * 128 + k) * 64 + j2]
                            : W2r[((size_t)m * 128 + k) * 64 + (j2 - 64)];
        Wcat2[((size_t)m * 128 + j2) * 128 + k] = (ushort)f2bf(v);
    }
}

// ============ MFMA GEMM1: t1 (fp8) and r1 (bf16, +b1) = x @ {W1l, W1r} ============
// Epilogue staged through Bs (free after MFMA) -> fully coalesced uint4 stores.
__global__ __launch_bounds__(256) void k_mfma1(
    const float* __restrict__ x, const ushort* __restrict__ Wcat1,
    const float* __restrict__ b1, uchar* __restrict__ t1, ushort* __restrict__ r1)
{
    const int m = blockIdx.y;
    const int row0 = blockIdx.x * 128;
    const int tid = threadIdx.x;
    const int lane = tid & 63, w = tid >> 6;
    const int wr = w >> 1, wc = w & 1;

    __shared__ ushort As[128][136];
    __shared__ ushort Bs[128][136];

    const float* Am = x + (size_t)m * Nn * 128;

    #pragma unroll
    for (int i = 0; i < 16; i++) {
        int f4 = tid + i * 256;
        int row = f4 >> 5, c4 = f4 & 31;
        int gr = row0 + row; if (gr >= Nn) gr = Nn - 1;
        float4 v = *(const float4*)(Am + (size_t)gr * 128 + c4 * 4);
        uint lo = f2bf(v.x) | (f2bf(v.y) << 16);
        uint hi = f2bf(v.z) | (f2bf(v.w) << 16);
        *(uint2*)&As[row][c4 * 4] = make_uint2(lo, hi);
    }

    for (int z = 0; z < 2; z++) {
        const ushort* Bm = Wcat1 + ((size_t)m * 256 + (size_t)z * 128) * 128;
        if (z) __syncthreads();   // flush reads done before overwriting Bs
        #pragma unroll
        for (int i = 0; i < 8; i++) {
            int c8 = tid + i * 256;
            int row = c8 >> 4, c = c8 & 15;
            *(bf16x8*)&Bs[row][c * 8] = *(const bf16x8*)(Bm + (size_t)row * 128 + c * 8);
        }
        __syncthreads();

        f32x4 acc[4][4];
        #pragma unroll
        for (int i = 0; i < 4; i++)
            #pragma unroll
            for (int j = 0; j < 4; j++) acc[i][j] = (f32x4){0.f, 0.f, 0.f, 0.f};

        #pragma unroll
        for (int ks = 0; ks < 4; ks++) {
            bf16x8 a[4], b[4];
            #pragma unroll
            for (int i = 0; i < 4; i++)
                a[i] = *(const bf16x8*)&As[wr * 64 + i * 16 + (lane & 15)][ks * 32 + (lane >> 4) * 8];
            #pragma unroll
            for (int j = 0; j < 4; j++)
                b[j] = *(const bf16x8*)&Bs[wc * 64 + j * 16 + (lane & 15)][ks * 32 + (lane >> 4) * 8];
            #pragma unroll
            for (int i = 0; i < 4; i++)
                #pragma unroll
                for (int j = 0; j < 4; j++)
                    acc[i][j] = mfma16(a[i], b[j], acc[i][j]);
        }

        __syncthreads();   // all Bs fragment reads complete -> reuse Bs as staging
        if (z == 0) {
            uchar* stg = (uchar*)&Bs[0][0];   // 128x128 fp8 = 16KB
            #pragma unroll
            for (int j = 0; j < 4; j++) {
                int col = wc * 64 + j * 16 + (lane & 15);
                #pragma unroll
                for (int i = 0; i < 4; i++) {
                    #pragma unroll
                    for (int q = 0; q < 4; q++) {
                        int row = wr * 64 + i * 16 + (lane >> 4) * 4 + q;
                        stg[row * 128 + col] = f2fp8(acc[i][j][q]);
                    }
                }
            }
            __syncthreads();
            uchar* outp = t1 + (size_t)m * Nn * 128 + (size_t)row0 * 128;
            #pragma unroll
            for (int i = 0; i < 4; i++) {
                int o = (tid + i * 256) * 16;
                if (row0 + (o >> 7) < Nn)
                    *(uint4*)(outp + o) = *(const uint4*)(stg + o);
            }
        } else {
            ushort* stg = &Bs[0][0];   // 128x128 bf16 = 32KB (Bs = 34.8KB)
            #pragma unroll
            for (int j = 0; j < 4; j++) {
                int col = wc * 64 + j * 16 + (lane & 15);
                float bias = b1[m * 128 + col];
                #pragma unroll
                for (int i = 0; i < 4; i++) {
                    #pragma unroll
                    for (int q = 0; q < 4; q++) {
                        int row = wr * 64 + i * 16 + (lane >> 4) * 4 + q;
                        stg[row * 128 + col] = (ushort)f2bf(acc[i][j][q] + bias);
                    }
                }
            }
            __syncthreads();
            ushort* outp = r1 + (size_t)m * Nn * 128 + (size_t)row0 * 128;
            #pragma unroll
            for (int i = 0; i < 8; i++) {
                int o = (tid + i * 256) * 8;   // ushort units, 16B granule
                if (row0 + (o >> 7) < Nn)
                    *(uint4*)(outp + o) = *(const uint4*)(stg + o);
            }
        }
    }
}

// ============ MFMA GEMM2: t2 (bf16) / r2 (bf16, +b2) = h @ Wcat2 ============
// Staged epilogue: t2 tile in Bs[0..8K), r2 tile in Bs[8K..16K) (ushort units).
__global__ __launch_bounds__(256) void k_mfma2(
    const ushort* __restrict__ h, const ushort* __restrict__ Wcat2,
    const float* __restrict__ b2, ushort* __restrict__ t2, ushort* __restrict__ r2)
{
    const int m = blockIdx.y;
    const int row0 = blockIdx.x * 128;
    const int tid = threadIdx.x;
    const int lane = tid & 63, w = tid >> 6;
    const int wr = w >> 1, wc = w & 1;

    __shared__ ushort As[128][136];
    __shared__ ushort Bs[128][136];

    const ushort* Am = h + (size_t)m * Nn * 128;
    const ushort* Bm = Wcat2 + (size_t)m * 128 * 128;

    #pragma unroll
    for (int i = 0; i < 8; i++) {
        int c8 = tid + i * 256;
        int row = c8 >> 4, c = c8 & 15;
        int gr = row0 + row; if (gr >= Nn) gr = Nn - 1;
        *(bf16x8*)&As[row][c * 8] = *(const bf16x8*)(Am + (size_t)gr * 128 + c * 8);
    }
    #pragma unroll
    for (int i = 0; i < 8; i++) {
        int c8 = tid + i * 256;
        int row = c8 >> 4, c = c8 & 15;
        *(bf16x8*)&Bs[row][c * 8] = *(const bf16x8*)(Bm + (size_t)row * 128 + c * 8);
    }
    __syncthreads();

    f32x4 acc[4][4];
    #pragma unroll
    for (int i = 0; i < 4; i++)
        #pragma unroll
        for (int j = 0; j < 4; j++) acc[i][j] = (f32x4){0.f, 0.f, 0.f, 0.f};

    #pragma unroll
    for (int ks = 0; ks < 4; ks++) {
        bf16x8 a[4], b[4];
        #pragma unroll
        for (int i = 0; i < 4; i++)
            a[i] = *(const bf16x8*)&As[wr * 64 + i * 16 + (lane & 15)][ks * 32 + (lane >> 4) * 8];
        #pragma unroll
        for (int j = 0; j < 4; j++)
            b[j] = *(const bf16x8*)&Bs[wc * 64 + j * 16 + (lane & 15)][ks * 32 + (lane >> 4) * 8];
        #pragma unroll
        for (int i = 0; i < 4; i++)
            #pragma unroll
            for (int j = 0; j < 4; j++)
                acc[i][j] = mfma16(a[i], b[j], acc[i][j]);
    }

    __syncthreads();   // Bs free -> staging
    ushort* stg = &Bs[0][0];
    ushort* my = stg + (wc ? 8192 : 0);   // 128x64 ushort tiles
    #pragma unroll
    for (int j = 0; j < 4; j++) {
        int cl = j * 16 + (lane & 15);
        float bias = wc ? b2[m * 64 + cl] : 0.0f;
        #pragma unroll
        for (int i = 0; i < 4; i++) {
            #pragma unroll
            for (int q = 0; q < 4; q++) {
                int row = wr * 64 + i * 16 + (lane >> 4) * 4 + q;
                my[row * 64 + cl] = (ushort)f2bf(acc[i][j][q] + bias);
            }
        }
    }
    __syncthreads();
    ushort* ot = t2 + (size_t)m * Nn * 64 + (size_t)row0 * 64;
    ushort* orr = r2 + (size_t)m * Nn * 64 + (size_t)row0 * 64;
    #pragma unroll
    for (int i = 0; i < 4; i++) {
        int o = (tid + i * 256) * 8;   // ushort units
        if (row0 + (o >> 6) < Nn) {
            *(uint4*)(ot + o)  = *(const uint4*)(stg + o);
            *(uint4*)(orr + o) = *(const uint4*)(stg + 8192 + o);
        }
    }
}

// ============ agg1: h = ELU(mean-gather(t1 fp8) + r1), bf16 out ============
// One 8-lane group per node; 4-edge-deep gather pipeline (4 loads in flight).
__global__ __launch_bounds__(256) void k_agg_elu(
    const uchar* __restrict__ t1, const ushort* __restrict__ r1,
    const int* __restrict__ off, const int* __restrict__ cnt,
    const float* __restrict__ inv, const ushort* __restrict__ esrc,
    ushort* __restrict__ h)
{
    int lane = threadIdx.x & 63;
    int grp = lane >> 3;
    int sub = lane & 7;
    int node = ((blockIdx.x * 256 + threadIdx.x) >> 6) * 8 + grp;
    if (node >= METAc * Nn) return;
    int m = node / Nn, n = node - m * Nn;
    int start = off[m * Nn + n];
    int c = cnt[m * Nn + n];
    const ushort* es = esrc + (size_t)m * Ee + start;
    const uchar* tm = t1 + (size_t)m * Nn * 128;

    f32x2 a[8];
    #pragma unroll
    for (int k = 0; k < 8; k++) a[k] = (f32x2){0.f, 0.f};

    int e = 0;
    for (; e + 3 < c; e += 4) {
        int s0 = es[e], s1 = es[e + 1], s2 = es[e + 2], s3 = es[e + 3];
        uint4 v0 = *(const uint4*)(tm + (size_t)s0 * 128 + sub * 16);
        uint4 v1 = *(const uint4*)(tm + (size_t)s1 * 128 + sub * 16);
        uint4 v2 = *(const uint4*)(tm + (size_t)s2 * 128 + sub * 16);
        uint4 v3 = *(const uint4*)(tm + (size_t)s3 * 128 + sub * 16);
        a[0] += CVT8LO(v0.x); a[1] += CVT8HI(v0.x);
        a[2] += CVT8LO(v0.y); a[3] += CVT8HI(v0.y);
        a[4] += CVT8LO(v0.z); a[5] += CVT8HI(v0.z);
        a[6] += CVT8LO(v0.w); a[7] += CVT8HI(v0.w);
        a[0] += CVT8LO(v1.x); a[1] += CVT8HI(v1.x);
        a[2] += CVT8LO(v1.y); a[3] += CVT8HI(v1.y);
        a[4] += CVT8LO(v1.z); a[5] += CVT8HI(v1.z);
        a[6] += CVT8LO(v1.w); a[7] += CVT8HI(v1.w);
        a[0] += CVT8LO(v2.x); a[1] += CVT8HI(v2.x);
        a[2] += CVT8LO(v2.y); a[3] += CVT8HI(v2.y);
        a[4] += CVT8LO(v2.z); a[5] += CVT8HI(v2.z);
        a[6] += CVT8LO(v2.w); a[7] += CVT8HI(v2.w);
        a[0] += CVT8LO(v3.x); a[1] += CVT8HI(v3.x);
        a[2] += CVT8LO(v3.y); a[3] += CVT8HI(v3.y);
        a[4] += CVT8LO(v3.z); a[5] += CVT8HI(v3.z);
        a[6] += CVT8LO(v3.w); a[7] += CVT8HI(v3.w);
    }
    for (; e < c; e++) {
        int s0 = es[e];
        uint4 v0 = *(const uint4*)(tm + (size_t)s0 * 128 + sub * 16);
        a[0] += CVT8LO(v0.x); a[1] += CVT8HI(v0.x);
        a[2] += CVT8LO(v0.y); a[3] += CVT8HI(v0.y);
        a[4] += CVT8LO(v0.z); a[5] += CVT8HI(v0.z);
        a[6] += CVT8LO(v0.w); a[7] += CVT8HI(v0.w);
    }

    float iv = inv[m * Nn + n];
    const uint* rrow = (const uint*)(r1 + ((size_t)m * Nn + n) * 128);
    uint4 rv0 = *(const uint4*)(rrow + sub * 8);
    uint4 rv1 = *(const uint4*)(rrow + sub * 8 + 4);
    uint rw[8] = {rv0.x, rv0.y, rv0.z, rv0.w, rv1.x, rv1.y, rv1.z, rv1.w};
    uint o[8];
    #pragma unroll
    for (int k = 0; k < 8; k++) {
        float z0 = a[k].x * iv + bf2f(rw[k] & 0xffffu);
        float z1 = a[k].y * iv + bf2f(rw[k] >> 16);
        z0 = z0 > 0.0f ? z0 : (__expf(z0) - 1.0f);
        z1 = z1 > 0.0f ? z1 : (__expf(z1) - 1.0f);
        o[k] = f2bf(z0) | (f2bf(z1) << 16);
    }
    uint* hrow = (uint*)(h + ((size_t)m * Nn + n) * 128) + sub * 8;
    *(uint4*)hrow       = make_uint4(o[0], o[1], o[2], o[3]);
    *(uint4*)(hrow + 4) = make_uint4(o[4], o[5], o[6], o[7]);
}

// ============ agg2: out = log_softmax(mean-gather(t2 bf16) + r2) ============
// One 8-lane group per node; 4-edge-deep gather pipeline.
__global__ __launch_bounds__(256) void k_agg_lsm(
    const ushort* __restrict__ t2, const ushort* __restrict__ r2,
    const int* __restrict__ off, const int* __restrict__ cnt,
    const float* __restrict__ inv, const ushort* __restrict__ esrc,
    float* __restrict__ out)
{
    int lane = threadIdx.x & 63;
    int grp = lane >> 3;
    int sub = lane & 7;
    int node = ((blockIdx.x * 256 + threadIdx.x) >> 6) * 8 + grp;
    if (node >= METAc * Nn) return;
    int m = node / Nn, n = node - m * Nn;
    int start = off[m * Nn + n];
    int c = cnt[m * Nn + n];
    const ushort* es = esrc + (size_t)m * Ee + start;
    const ushort* tm = t2 + (size_t)m * Nn * 64;

    f32x2 a[4];
    #pragma unroll
    for (int k = 0; k < 4; k++) a[k] = (f32x2){0.f, 0.f};

    int e = 0;
    for (; e + 3 < c; e += 4) {
        int s0 = es[e], s1 = es[e + 1], s2 = es[e + 2], s3 = es[e + 3];
        uint4 v0 = *(const uint4*)(tm + (size_t)s0 * 64 + sub * 8);
        uint4 v1 = *(const uint4*)(tm + (size_t)s1 * 64 + sub * 8);
        uint4 v2 = *(const uint4*)(tm + (size_t)s2 * 64 + sub * 8);
        uint4 v3 = *(const uint4*)(tm + (size_t)s3 * 64 + sub * 8);
        a[0] += up2(v0.x); a[1] += up2(v0.y); a[2] += up2(v0.z); a[3] += up2(v0.w);
        a[0] += up2(v1.x); a[1] += up2(v1.y); a[2] += up2(v1.z); a[3] += up2(v1.w);
        a[0] += up2(v2.x); a[1] += up2(v2.y); a[2] += up2(v2.z); a[3] += up2(v2.w);
        a[0] += up2(v3.x); a[1] += up2(v3.y); a[2] += up2(v3.z); a[3] += up2(v3.w);
    }
    for (; e < c; e++) {
        int s0 = es[e];
        uint4 v0 = *(const uint4*)(tm + (size_t)s0 * 64 + sub * 8);
        a[0] += up2(v0.x); a[1] += up2(v0.y); a[2] += up2(v0.z); a[3] += up2(v0.w);
    }

    float iv = inv[m * Nn + n];
    uint4 rv = *(const uint4*)(r2 + ((size_t)m * Nn + n) * 64 + sub * 8);
    uint rr[4] = {rv.x, rv.y, rv.z, rv.w};
    float z[8];
    #pragma unroll
    for (int k = 0; k < 4; k++) {
        z[2 * k]     = a[k].x * iv + bf2f(rr[k] & 0xffffu);
        z[2 * k + 1] = a[k].y * iv + bf2f(rr[k] >> 16);
    }
    float mx = z[0];
    #pragma unroll
    for (int k = 1; k < 8; k++) mx = fmaxf(mx, z[k]);
    #pragma unroll
    for (int o = 1; o <= 4; o <<= 1) mx = fmaxf(mx, __shfl_xor(mx, o));
    float s = 0.0f;
    #pragma unroll
    for (int k = 0; k < 8; k++) s += __expf(z[k] - mx);
    #pragma unroll
    for (int o = 1; o <= 4; o <<= 1) s += __shfl_xor(s, o);
    float lse = mx + __logf(s);
    float* op = out + ((size_t)m * Nn + n) * 64 + sub * 8;
    *(float4*)op       = make_float4(z[0] - lse, z[1] - lse, z[2] - lse, z[3] - lse);
    *(float4*)(op + 4) = make_float4(z[4] - lse, z[5] - lse, z[6] - lse, z[7] - lse);
}

extern "C" void kernel_launch(void* const* d_in, const int* in_sizes, int n_in,
                              void* d_out, int out_size, void* d_ws, size_t ws_size,
                              hipStream_t stream) {
    const float* meta_x = (const float*)d_in[0];
    const int*   ei     = (const int*)d_in[1];
    const float* W1l    = (const float*)d_in[2];
    const float* W1r    = (const float*)d_in[3];
    const float* b1     = (const float*)d_in[4];
    const float* W2l    = (const float*)d_in[5];
    const float* W2r    = (const float*)d_in[6];
    const float* b2     = (const float*)d_in[7];
    float* out = (float*)d_out;

    const size_t nN = (size_t)METAc * Nn;

    float* inv   = (float*)d_ws;                         // nN
    int*   cnt   = (int*)(inv + nN);                     // nN
    int*   off   = cnt + nN;                             // nN
    int*   ghist = off + nN;                             // METAc*NCHK*BKT
    int*   sofs  = ghist + (size_t)METAc * NCHK * BKT;   // METAc*BKT*NCHK
    int*   totals= sofs + (size_t)METAc * BKT * NCHK;    // METAc*BKT
    int*   bbase = totals + METAc * BKT;                 // METAc*BKT
    uint*  packed= (uint*)(bbase + METAc * BKT);         // METAc*Ee
    uint*  mid   = packed + (size_t)METAc * Ee;          // METAc*Ee
    ushort* esrc = (ushort*)(mid + (size_t)METAc * Ee);  // METAc*Ee
    uchar* t1    = (uchar*)(esrc + (size_t)METAc * Ee);  // nN*128 fp8
    ushort* r1   = (ushort*)(t1 + nN * 128);
    ushort* h    = r1 + nN * 128;
    ushort* t2   = h + nN * 128;                         // nN*64 bf16
    ushort* r2   = t2 + nN * 64;
    ushort* Wcat1 = r2 + nN * 64;
    ushort* Wcat2 = Wcat1 + (size_t)METAc * 256 * 128;

    k_packhist<<<METAc * NCHK, 256, 0, stream>>>(ei, packed, ghist);
    k_bscan<<<METAc * BKT, 1024, 0, stream>>>(ghist, sofs, totals);
    k_bbase<<<METAc, 256, 0, stream>>>(totals, bbase);
    k_scatterP<<<METAc * NCHK, 256, 0, stream>>>(packed, sofs, bbase, mid);
    k_binb<<<METAc * BKT, 256, 0, stream>>>(mid, bbase, off, cnt, inv, esrc);
    k_wcat<<<(METAc * 384 * 128 + 255) / 256, 256, 0, stream>>>(W1l, W1r, W2l, W2r, Wcat1, Wcat2);

    k_mfma1<<<dim3((Nn + 127) / 128, METAc), 256, 0, stream>>>(meta_x, Wcat1, b1, t1, r1);
    k_agg_elu<<<(METAc * Nn / 8 + 255) / 256 * 64, 256, 0, stream>>>(t1, r1, off, cnt, inv, esrc, h);
    k_mfma2<<<dim3((Nn + 127) / 128, METAc), 256, 0, stream>>>(h, Wcat2, b2, t2, r2);
    k_agg_lsm<<<(METAc * Nn / 8 + 255) / 256 * 64, 256, 0, stream>>>(t2, r2, off, cnt, inv, esrc, out);
}

// Round 22
// 190.858 us; speedup vs baseline: 3.2991x; 1.0868x over previous
//
#include <hip/hip_runtime.h>

#define METAc 3
#define Nn 50000
#define Ee 640000
#define BKT 200      // dst buckets per graph
#define BN 250       // nodes per bucket (200*250 = 50000 exact)
#define NCHK 625     // 1024-edge chunks per graph (625*1024 = 640000 exact)
#define SEGCAP 4608  // LDS edge cap per bucket (mean 3200, sigma 57 -> +24 sigma)

typedef unsigned int uint;
typedef unsigned short ushort;
typedef unsigned char uchar;
typedef __attribute__((ext_vector_type(8))) short bf16x8;
typedef __attribute__((ext_vector_type(4))) float f32x4;
typedef __attribute__((ext_vector_type(2))) float f32x2;
typedef __attribute__((ext_vector_type(4))) uint uint4v;

#define CVT8LO(w) ((f32x2)__builtin_amdgcn_cvt_pk_f32_fp8((w), false))
#define CVT8HI(w) ((f32x2)__builtin_amdgcn_cvt_pk_f32_fp8((w), true))

__device__ __forceinline__ float bf2f(uint u16) {
    union { uint u; float f; } v; v.u = u16 << 16; return v.f;
}
__device__ __forceinline__ uint f2bf(float f) {
    union { float f; uint u; } v; v.f = f;
    return (v.u + 0x7fffu + ((v.u >> 16) & 1u)) >> 16;
}
__device__ __forceinline__ uchar f2fp8(float f) {
    return (uchar)(__builtin_amdgcn_cvt_pk_fp8_f32(f, f, 0u, false) & 0xffu);
}
__device__ __forceinline__ f32x2 up2(uint u) {
    union { uint2 u2; f32x2 f; } cv;
    cv.u2.x = u << 16;
    cv.u2.y = u & 0xffff0000u;
    return cv.f;
}
__device__ __forceinline__ f32x4 mfma16(bf16x8 a, bf16x8 b, f32x4 c) {
    return __builtin_amdgcn_mfma_f32_16x16x32_bf16(a, b, c, 0, 0, 0);
}
__device__ __forceinline__ uint4v nt_load4(const void* p) {
    return __builtin_nontemporal_load((const uint4v*)p);
}

// ===== 1) pack + per-chunk bucket histogram (no global atomics) =====
__global__ __launch_bounds__(256) void k_packhist(const int* __restrict__ ei,
                                                  uint* __restrict__ packed,
                                                  int* __restrict__ ghist) {
    const int m = blockIdx.x / NCHK;
    const int b = blockIdx.x - m * NCHK;
    const int t = threadIdx.x;
    __shared__ int hist[BKT];
    if (t < BKT) hist[t] = 0;
    __syncthreads();

    const int e4 = b * 256 + t;                 // uint4 index within graph
    const int* base = ei + (size_t)m * 2 * Ee;
    uint4v d = nt_load4(base + Ee + e4 * 4);
    uint4v s = nt_load4(base + e4 * 4);
    uint4v p;
    p.x = (s.x & 0xffffu) | (d.x << 16);
    p.y = (s.y & 0xffffu) | (d.y << 16);
    p.z = (s.z & 0xffffu) | (d.z << 16);
    p.w = (s.w & 0xffffu) | (d.w << 16);
    *(uint4v*)(packed + (size_t)m * Ee + e4 * 4) = p;
    atomicAdd(&hist[(int)(d.x) / BN], 1);
    atomicAdd(&hist[(int)(d.y) / BN], 1);
    atomicAdd(&hist[(int)(d.z) / BN], 1);
    atomicAdd(&hist[(int)(d.w) / BN], 1);
    __syncthreads();
    if (t < BKT) ghist[((size_t)m * NCHK + b) * BKT + t] = hist[t];
}

// ===== 2) per-(m,bucket) exclusive scan over chunks -> sofs, totals =====
__global__ __launch_bounds__(1024) void k_bscan(const int* __restrict__ ghist,
                                                int* __restrict__ sofs,
                                                int* __restrict__ totals) {
    const int m = blockIdx.x / BKT;
    const int k = blockIdx.x - m * BKT;
    const int t = threadIdx.x;
    __shared__ int sc[1024];
    int v = (t < NCHK) ? ghist[((size_t)m * NCHK + t) * BKT + k] : 0;
    sc[t] = v;
    __syncthreads();
    for (int st = 1; st < 1024; st <<= 1) {
        int add = (t >= st) ? sc[t - st] : 0;
        __syncthreads();
        sc[t] += add;
        __syncthreads();
    }
    if (t < NCHK) sofs[((size_t)m * BKT + k) * NCHK + t] = sc[t] - v;
    if (t == NCHK - 1) totals[m * BKT + k] = sc[t];
}

// ===== 3) per-graph scan of bucket totals -> bucket bases =====
__global__ __launch_bounds__(256) void k_bbase(const int* __restrict__ totals,
                                               int* __restrict__ bbase) {
    const int m = blockIdx.x;
    const int t = threadIdx.x;
    __shared__ int sc[256];
    int v = (t < BKT) ? totals[m * BKT + t] : 0;
    sc[t] = v;
    __syncthreads();
    for (int st = 1; st < 256; st <<= 1) {
        int add = (t >= st) ? sc[t - st] : 0;
        __syncthreads();
        sc[t] += add;
        __syncthreads();
    }
    if (t < BKT) bbase[m * BKT + t] = sc[t] - v;
}

// ===== 4) bucket partition: packed -> mid (LDS cursors, no global atomics) =====
__global__ __launch_bounds__(256) void k_scatterP(const uint* __restrict__ packed,
                                                  const int* __restrict__ sofs,
                                                  const int* __restrict__ bbase,
                                                  uint* __restrict__ mid) {
    const int m = blockIdx.x / NCHK;
    const int b = blockIdx.x - m * NCHK;
    const int t = threadIdx.x;
    __shared__ int curs[BKT];
    if (t < BKT)
        curs[t] = bbase[m * BKT + t] + sofs[((size_t)m * BKT + t) * NCHK + b];
    __syncthreads();

    const int e4 = b * 256 + t;
    uint4v p = *(const uint4v*)(packed + (size_t)m * Ee + e4 * 4);
    uint* mm = mid + (size_t)m * Ee;
    int kk, pos;
    kk = (int)(p.x >> 16) / BN; pos = atomicAdd(&curs[kk], 1); mm[pos] = p.x;
    kk = (int)(p.y >> 16) / BN; pos = atomicAdd(&curs[kk], 1); mm[pos] = p.y;
    kk = (int)(p.z >> 16) / BN; pos = atomicAdd(&curs[kk], 1); mm[pos] = p.z;
    kk = (int)(p.w >> 16) / BN; pos = atomicAdd(&curs[kk], 1); mm[pos] = p.w;
}

// ===== 5) per-bucket bin: mid -> esrc (coalesced), also off/cnt/inv =====
__global__ __launch_bounds__(256) void k_binb(const uint* __restrict__ mid,
                                              const int* __restrict__ bbase,
                                              int* __restrict__ off,
                                              int* __restrict__ cnt,
                                              float* __restrict__ inv,
                                              ushort* __restrict__ esrc) {
    const int m = blockIdx.x / BKT;
    const int k = blockIdx.x - m * BKT;
    const int t = threadIdx.x;
    const int n0 = k * BN;
    const int sbase = bbase[m * BKT + k];
    const int send = (k < BKT - 1) ? bbase[m * BKT + k + 1] : Ee;
    const int seglen = send - sbase;

    __shared__ uint seg[SEGCAP];
    __shared__ ushort outs[SEGCAP];
    __shared__ int lcnt[BN];
    __shared__ int lcur[BN];
    __shared__ int sc[256];

    const uint* mm = mid + (size_t)m * Ee + sbase;
    ushort* em = esrc + (size_t)m * Ee + sbase;
    const bool fits = seglen <= SEGCAP;

    if (fits)
        for (int i = t; i < seglen; i += 256) seg[i] = mm[i];
    if (t < BN) lcnt[t] = 0;
    __syncthreads();

    for (int i = t; i < seglen; i += 256) {
        uint p = fits ? seg[i] : mm[i];
        atomicAdd(&lcnt[(int)(p >> 16) - n0], 1);
    }
    __syncthreads();

    int v = (t < BN) ? lcnt[t] : 0;
    sc[t] = v;
    __syncthreads();
    for (int st = 1; st < 256; st <<= 1) {
        int add = (t >= st) ? sc[t - st] : 0;
        __syncthreads();
        sc[t] += add;
        __syncthreads();
    }
    if (t < BN) {
        int excl = sc[t] - v;
        lcur[t] = excl;
        int node = m * Nn + n0 + t;
        off[node] = sbase + excl;
        cnt[node] = v;
        inv[node] = 1.0f / fmaxf((float)v, 1.0f);
    }
    __syncthreads();

    if (fits) {
        for (int i = t; i < seglen; i += 256) {
            uint p = seg[i];
            int pos = atomicAdd(&lcur[(int)(p >> 16) - n0], 1);
            outs[pos] = (ushort)(p & 0xffffu);
        }
        __syncthreads();
        for (int i = t; i < seglen; i += 256) em[i] = outs[i];
    } else {
        for (int i = t; i < seglen; i += 256) {
            uint p = mm[i];
            int pos = atomicAdd(&lcur[(int)(p >> 16) - n0], 1);
            em[pos] = (ushort)(p & 0xffffu);
        }
    }
}

// ============ weight prep ============
__global__ __launch_bounds__(256) void k_wcat(
    const float* __restrict__ W1l, const float* __restrict__ W1r,
    const float* __restrict__ W2l, const float* __restrict__ W2r,
    ushort* __restrict__ Wcat1, ushort* __restrict__ Wcat2)
{
    int idx = blockIdx.x * 256 + threadIdx.x;
    if (idx >= METAc * 384 * 128) return;
    int m = idx / (384 * 128);
    int rem = idx - m * 384 * 128;
    int j = rem >> 7;
    int k = rem & 127;
    if (j < 256) {
        float v = (j < 128) ? W1l[((size_t)m * 128 + k) * 128 + j]
                            : W1r[((size_t)m * 128 + k) * 128 + (j - 128)];
        Wcat1[((size_t)m * 256 + j) * 128 + k] = (ushort)f2bf(v);
    } else {
        int j2 = j - 256;
        float v = (j2 < 64) ? W2l[((size_t)m * 128 + k) * 64 + j2]
                            : W2r[((size_t)m * 128 + k) * 64 + (j2 - 64)];
        Wcat2[((size_t)m * 128 + j2) * 128 + k] = (ushort)f2bf(v);
    }
}

// ============ MFMA GEMM1: t1 (fp8) and r1 (bf16, +b1) = x @ {W1l, W1r} ============
// Epilogue staged through Bs (free after MFMA) -> fully coalesced uint4 stores.
__global__ __launch_bounds__(256) void k_mfma1(
    const float* __restrict__ x, const ushort* __restrict__ Wcat1,
    const float* __restrict__ b1, uchar* __restrict__ t1, ushort* __restrict__ r1)
{
    const int m = blockIdx.y;
    const int row0 = blockIdx.x * 128;
    const int tid = threadIdx.x;
    const int lane = tid & 63, w = tid >> 6;
    const int wr = w >> 1, wc = w & 1;

    __shared__ ushort As[128][136];
    __shared__ ushort Bs[128][136];

    const float* Am = x + (size_t)m * Nn * 128;

    #pragma unroll
    for (int i = 0; i < 16; i++) {
        int f4 = tid + i * 256;
        int row = f4 >> 5, c4 = f4 & 31;
        int gr = row0 + row; if (gr >= Nn) gr = Nn - 1;
        float4 v = *(const float4*)(Am + (size_t)gr * 128 + c4 * 4);
        uint lo = f2bf(v.x) | (f2bf(v.y) << 16);
        uint hi = f2bf(v.z) | (f2bf(v.w) << 16);
        *(uint2*)&As[row][c4 * 4] = make_uint2(lo, hi);
    }

    for (int z = 0; z < 2; z++) {
        const ushort* Bm = Wcat1 + ((size_t)m * 256 + (size_t)z * 128) * 128;
        if (z) __syncthreads();
        #pragma unroll
        for (int i = 0; i < 8; i++) {
            int c8 = tid + i * 256;
            int row = c8 >> 4, c = c8 & 15;
            *(bf16x8*)&Bs[row][c * 8] = *(const bf16x8*)(Bm + (size_t)row * 128 + c * 8);
        }
        __syncthreads();

        f32x4 acc[4][4];
        #pragma unroll
        for (int i = 0; i < 4; i++)
            #pragma unroll
            for (int j = 0; j < 4; j++) acc[i][j] = (f32x4){0.f, 0.f, 0.f, 0.f};

        #pragma unroll
        for (int ks = 0; ks < 4; ks++) {
            bf16x8 a[4], b[4];
            #pragma unroll
            for (int i = 0; i < 4; i++)
                a[i] = *(const bf16x8*)&As[wr * 64 + i * 16 + (lane & 15)][ks * 32 + (lane >> 4) * 8];
            #pragma unroll
            for (int j = 0; j < 4; j++)
                b[j] = *(const bf16x8*)&Bs[wc * 64 + j * 16 + (lane & 15)][ks * 32 + (lane >> 4) * 8];
            #pragma unroll
            for (int i = 0; i < 4; i++)
                #pragma unroll
                for (int j = 0; j < 4; j++)
                    acc[i][j] = mfma16(a[i], b[j], acc[i][j]);
        }

        __syncthreads();   // all Bs fragment reads complete -> reuse Bs as staging
        if (z == 0) {
            uchar* stg = (uchar*)&Bs[0][0];   // 128x128 fp8 = 16KB
            #pragma unroll
            for (int j = 0; j < 4; j++) {
                int col = wc * 64 + j * 16 + (lane & 15);
                #pragma unroll
                for (int i = 0; i < 4; i++) {
                    #pragma unroll
                    for (int q = 0; q < 4; q++) {
                        int row = wr * 64 + i * 16 + (lane >> 4) * 4 + q;
                        stg[row * 128 + col] = f2fp8(acc[i][j][q]);
                    }
                }
            }
            __syncthreads();
            uchar* outp = t1 + (size_t)m * Nn * 128 + (size_t)row0 * 128;
            #pragma unroll
            for (int i = 0; i < 4; i++) {
                int o = (tid + i * 256) * 16;
                if (row0 + (o >> 7) < Nn)
                    *(uint4*)(outp + o) = *(const uint4*)(stg + o);
            }
        } else {
            ushort* stg = &Bs[0][0];   // 128x128 bf16 = 32KB (Bs = 34.8KB)
            #pragma unroll
            for (int j = 0; j < 4; j++) {
                int col = wc * 64 + j * 16 + (lane & 15);
                float bias = b1[m * 128 + col];
                #pragma unroll
                for (int i = 0; i < 4; i++) {
                    #pragma unroll
                    for (int q = 0; q < 4; q++) {
                        int row = wr * 64 + i * 16 + (lane >> 4) * 4 + q;
                        stg[row * 128 + col] = (ushort)f2bf(acc[i][j][q] + bias);
                    }
                }
            }
            __syncthreads();
            ushort* outp = r1 + (size_t)m * Nn * 128 + (size_t)row0 * 128;
            #pragma unroll
            for (int i = 0; i < 8; i++) {
                int o = (tid + i * 256) * 8;   // ushort units, 16B granule
                if (row0 + (o >> 7) < Nn)
                    *(uint4*)(outp + o) = *(const uint4*)(stg + o);
            }
        }
    }
}

// ============ MFMA GEMM2: t2 (fp8) / r2 (bf16, +b2) = h @ Wcat2 ============
// Staged epilogue: t2 fp8 tile at stg[0..8K)B, r2 bf16 tile at stg[8K..24K)B.
__global__ __launch_bounds__(256) void k_mfma2(
    const ushort* __restrict__ h, const ushort* __restrict__ Wcat2,
    const float* __restrict__ b2, uchar* __restrict__ t2, ushort* __restrict__ r2)
{
    const int m = blockIdx.y;
    const int row0 = blockIdx.x * 128;
    const int tid = threadIdx.x;
    const int lane = tid & 63, w = tid >> 6;
    const int wr = w >> 1, wc = w & 1;

    __shared__ ushort As[128][136];
    __shared__ ushort Bs[128][136];

    const ushort* Am = h + (size_t)m * Nn * 128;
    const ushort* Bm = Wcat2 + (size_t)m * 128 * 128;

    #pragma unroll
    for (int i = 0; i < 8; i++) {
        int c8 = tid + i * 256;
        int row = c8 >> 4, c = c8 & 15;
        int gr = row0 + row; if (gr >= Nn) gr = Nn - 1;
        *(bf16x8*)&As[row][c * 8] = *(const bf16x8*)(Am + (size_t)gr * 128 + c * 8);
    }
    #pragma unroll
    for (int i = 0; i < 8; i++) {
        int c8 = tid + i * 256;
        int row = c8 >> 4, c = c8 & 15;
        *(bf16x8*)&Bs[row][c * 8] = *(const bf16x8*)(Bm + (size_t)row * 128 + c * 8);
    }
    __syncthreads();

    f32x4 acc[4][4];
    #pragma unroll
    for (int i = 0; i < 4; i++)
        #pragma unroll
        for (int j = 0; j < 4; j++) acc[i][j] = (f32x4){0.f, 0.f, 0.f, 0.f};

    #pragma unroll
    for (int ks = 0; ks < 4; ks++) {
        bf16x8 a[4], b[4];
        #pragma unroll
        for (int i = 0; i < 4; i++)
            a[i] = *(const bf16x8*)&As[wr * 64 + i * 16 + (lane & 15)][ks * 32 + (lane >> 4) * 8];
        #pragma unroll
        for (int j = 0; j < 4; j++)
            b[j] = *(const bf16x8*)&Bs[wc * 64 + j * 16 + (lane & 15)][ks * 32 + (lane >> 4) * 8];
        #pragma unroll
        for (int i = 0; i < 4; i++)
            #pragma unroll
            for (int j = 0; j < 4; j++)
                acc[i][j] = mfma16(a[i], b[j], acc[i][j]);
    }

    __syncthreads();   // Bs free -> staging
    uchar* stgb = (uchar*)&Bs[0][0];          // t2 fp8 tile: 128x64 = 8KB
    ushort* stgr = (ushort*)(stgb + 8192);    // r2 bf16 tile: 128x64 = 16KB
    #pragma unroll
    for (int j = 0; j < 4; j++) {
        int cl = j * 16 + (lane & 15);
        float bias = wc ? b2[m * 64 + cl] : 0.0f;
        #pragma unroll
        for (int i = 0; i < 4; i++) {
            #pragma unroll
            for (int q = 0; q < 4; q++) {
                int row = wr * 64 + i * 16 + (lane >> 4) * 4 + q;
                if (wc)
                    stgr[row * 64 + cl] = (ushort)f2bf(acc[i][j][q] + bias);
                else
                    stgb[row * 64 + cl] = f2fp8(acc[i][j][q]);
            }
        }
    }
    __syncthreads();
    uchar* ot = t2 + (size_t)m * Nn * 64 + (size_t)row0 * 64;
    ushort* orr = r2 + (size_t)m * Nn * 64 + (size_t)row0 * 64;
    #pragma unroll
    for (int i = 0; i < 2; i++) {       // t2: 8KB flush
        int o = (tid + i * 256) * 16;   // byte offset; row = o/64
        if (row0 + (o >> 6) < Nn)
            *(uint4*)(ot + o) = *(const uint4*)(stgb + o);
    }
    #pragma unroll
    for (int i = 0; i < 4; i++) {       // r2: 16KB flush
        int o = (tid + i * 256) * 8;    // ushort offset; row = o/64
        if (row0 + (o >> 6) < Nn)
            *(uint4*)(orr + o) = *(const uint4*)(stgr + o);
    }
}

// ============ agg1: h = ELU(mean-gather(t1 fp8) + r1), bf16 out ============
// One 8-lane group per node; 4-edge-deep gather pipeline (4 loads in flight).
__global__ __launch_bounds__(256) void k_agg_elu(
    const uchar* __restrict__ t1, const ushort* __restrict__ r1,
    const int* __restrict__ off, const int* __restrict__ cnt,
    const float* __restrict__ inv, const ushort* __restrict__ esrc,
    ushort* __restrict__ h)
{
    int lane = threadIdx.x & 63;
    int grp = lane >> 3;
    int sub = lane & 7;
    int node = ((blockIdx.x * 256 + threadIdx.x) >> 6) * 8 + grp;
    if (node >= METAc * Nn) return;
    int m = node / Nn, n = node - m * Nn;
    int start = off[m * Nn + n];
    int c = cnt[m * Nn + n];
    const ushort* es = esrc + (size_t)m * Ee + start;
    const uchar* tm = t1 + (size_t)m * Nn * 128;

    f32x2 a[8];
    #pragma unroll
    for (int k = 0; k < 8; k++) a[k] = (f32x2){0.f, 0.f};

    int e = 0;
    for (; e + 3 < c; e += 4) {
        int s0 = es[e], s1 = es[e + 1], s2 = es[e + 2], s3 = es[e + 3];
        uint4 v0 = *(const uint4*)(tm + (size_t)s0 * 128 + sub * 16);
        uint4 v1 = *(const uint4*)(tm + (size_t)s1 * 128 + sub * 16);
        uint4 v2 = *(const uint4*)(tm + (size_t)s2 * 128 + sub * 16);
        uint4 v3 = *(const uint4*)(tm + (size_t)s3 * 128 + sub * 16);
        a[0] += CVT8LO(v0.x); a[1] += CVT8HI(v0.x);
        a[2] += CVT8LO(v0.y); a[3] += CVT8HI(v0.y);
        a[4] += CVT8LO(v0.z); a[5] += CVT8HI(v0.z);
        a[6] += CVT8LO(v0.w); a[7] += CVT8HI(v0.w);
        a[0] += CVT8LO(v1.x); a[1] += CVT8HI(v1.x);
        a[2] += CVT8LO(v1.y); a[3] += CVT8HI(v1.y);
        a[4] += CVT8LO(v1.z); a[5] += CVT8HI(v1.z);
        a[6] += CVT8LO(v1.w); a[7] += CVT8HI(v1.w);
        a[0] += CVT8LO(v2.x); a[1] += CVT8HI(v2.x);
        a[2] += CVT8LO(v2.y); a[3] += CVT8HI(v2.y);
        a[4] += CVT8LO(v2.z); a[5] += CVT8HI(v2.z);
        a[6] += CVT8LO(v2.w); a[7] += CVT8HI(v2.w);
        a[0] += CVT8LO(v3.x); a[1] += CVT8HI(v3.x);
        a[2] += CVT8LO(v3.y); a[3] += CVT8HI(v3.y);
        a[4] += CVT8LO(v3.z); a[5] += CVT8HI(v3.z);
        a[6] += CVT8LO(v3.w); a[7] += CVT8HI(v3.w);
    }
    for (; e < c; e++) {
        int s0 = es[e];
        uint4 v0 = *(const uint4*)(tm + (size_t)s0 * 128 + sub * 16);
        a[0] += CVT8LO(v0.x); a[1] += CVT8HI(v0.x);
        a[2] += CVT8LO(v0.y); a[3] += CVT8HI(v0.y);
        a[4] += CVT8LO(v0.z); a[5] += CVT8HI(v0.z);
        a[6] += CVT8LO(v0.w); a[7] += CVT8HI(v0.w);
    }

    float iv = inv[m * Nn + n];
    const uint* rrow = (const uint*)(r1 + ((size_t)m * Nn + n) * 128);
    uint4 rv0 = *(const uint4*)(rrow + sub * 8);
    uint4 rv1 = *(const uint4*)(rrow + sub * 8 + 4);
    uint rw[8] = {rv0.x, rv0.y, rv0.z, rv0.w, rv1.x, rv1.y, rv1.z, rv1.w};
    uint o[8];
    #pragma unroll
    for (int k = 0; k < 8; k++) {
        float z0 = a[k].x * iv + bf2f(rw[k] & 0xffffu);
        float z1 = a[k].y * iv + bf2f(rw[k] >> 16);
        z0 = z0 > 0.0f ? z0 : (__expf(z0) - 1.0f);
        z1 = z1 > 0.0f ? z1 : (__expf(z1) - 1.0f);
        o[k] = f2bf(z0) | (f2bf(z1) << 16);
    }
    uint* hrow = (uint*)(h + ((size_t)m * Nn + n) * 128) + sub * 8;
    *(uint4*)hrow       = make_uint4(o[0], o[1], o[2], o[3]);
    *(uint4*)(hrow + 4) = make_uint4(o[4], o[5], o[6], o[7]);
}

// ============ agg2: out = log_softmax(mean-gather(t2 fp8) + r2) ============
// One 8-lane group per node; t2 row = 64B fp8 -> uint2/lane; 4-deep pipeline.
__global__ __launch_bounds__(256) void k_agg_lsm(
    const uchar* __restrict__ t2, const ushort* __restrict__ r2,
    const int* __restrict__ off, const int* __restrict__ cnt,
    const float* __restrict__ inv, const ushort* __restrict__ esrc,
    float* __restrict__ out)
{
    int lane = threadIdx.x & 63;
    int grp = lane >> 3;
    int sub = lane & 7;       // 8B chunk = 8 fp8 cols
    int node = ((blockIdx.x * 256 + threadIdx.x) >> 6) * 8 + grp;
    if (node >= METAc * Nn) return;
    int m = node / Nn, n = node - m * Nn;
    int start = off[m * Nn + n];
    int c = cnt[m * Nn + n];
    const ushort* es = esrc + (size_t)m * Ee + start;
    const uchar* tm = t2 + (size_t)m * Nn * 64;

    f32x2 a[4];
    #pragma unroll
    for (int k = 0; k < 4; k++) a[k] = (f32x2){0.f, 0.f};

    int e = 0;
    for (; e + 3 < c; e += 4) {
        int s0 = es[e], s1 = es[e + 1], s2 = es[e + 2], s3 = es[e + 3];
        uint2 v0 = *(const uint2*)(tm + (size_t)s0 * 64 + sub * 8);
        uint2 v1 = *(const uint2*)(tm + (size_t)s1 * 64 + sub * 8);
        uint2 v2 = *(const uint2*)(tm + (size_t)s2 * 64 + sub * 8);
        uint2 v3 = *(const uint2*)(tm + (size_t)s3 * 64 + sub * 8);
        a[0] += CVT8LO(v0.x); a[1] += CVT8HI(v0.x);
        a[2] += CVT8LO(v0.y); a[3] += CVT8HI(v0.y);
        a[0] += CVT8LO(v1.x); a[1] += CVT8HI(v1.x);
        a[2] += CVT8LO(v1.y); a[3] += CVT8HI(v1.y);
        a[0] += CVT8LO(v2.x); a[1] += CVT8HI(v2.x);
        a[2] += CVT8LO(v2.y); a[3] += CVT8HI(v2.y);
        a[0] += CVT8LO(v3.x); a[1] += CVT8HI(v3.x);
        a[2] += CVT8LO(v3.y); a[3] += CVT8HI(v3.y);
    }
    for (; e < c; e++) {
        int s0 = es[e];
        uint2 v0 = *(const uint2*)(tm + (size_t)s0 * 64 + sub * 8);
        a[0] += CVT8LO(v0.x); a[1] += CVT8HI(v0.x);
        a[2] += CVT8LO(v0.y); a[3] += CVT8HI(v0.y);
    }

    float iv = inv[m * Nn + n];
    uint4 rv = *(const uint4*)(r2 + ((size_t)m * Nn + n) * 64 + sub * 8);
    uint rr[4] = {rv.x, rv.y, rv.z, rv.w};
    float z[8];
    #pragma unroll
    for (int k = 0; k < 4; k++) {
        z[2 * k]     = a[k].x * iv + bf2f(rr[k] & 0xffffu);
        z[2 * k + 1] = a[k].y * iv + bf2f(rr[k] >> 16);
    }
    float mx = z[0];
    #pragma unroll
    for (int k = 1; k < 8; k++) mx = fmaxf(mx, z[k]);
    #pragma unroll
    for (int o = 1; o <= 4; o <<= 1) mx = fmaxf(mx, __shfl_xor(mx, o));
    float s = 0.0f;
    #pragma unroll
    for (int k = 0; k < 8; k++) s += __expf(z[k] - mx);
    #pragma unroll
    for (int o = 1; o <= 4; o <<= 1) s += __shfl_xor(s, o);
    float lse = mx + __logf(s);
    float* op = out + ((size_t)m * Nn + n) * 64 + sub * 8;
    *(float4*)op       = make_float4(z[0] - lse, z[1] - lse, z[2] - lse, z[3] - lse);
    *(float4*)(op + 4) = make_float4(z[4] - lse, z[5] - lse, z[6] - lse, z[7] - lse);
}

extern "C" void kernel_launch(void* const* d_in, const int* in_sizes, int n_in,
                              void* d_out, int out_size, void* d_ws, size_t ws_size,
                              hipStream_t stream) {
    const float* meta_x = (const float*)d_in[0];
    const int*   ei     = (const int*)d_in[1];
    const float* W1l    = (const float*)d_in[2];
    const float* W1r    = (const float*)d_in[3];
    const float* b1     = (const float*)d_in[4];
    const float* W2l    = (const float*)d_in[5];
    const float* W2r    = (const float*)d_in[6];
    const float* b2     = (const float*)d_in[7];
    float* out = (float*)d_out;

    const size_t nN = (size_t)METAc * Nn;

    float* inv   = (float*)d_ws;                         // nN
    int*   cnt   = (int*)(inv + nN);                     // nN
    int*   off   = cnt + nN;                             // nN
    int*   ghist = off + nN;                             // METAc*NCHK*BKT
    int*   sofs  = ghist + (size_t)METAc * NCHK * BKT;   // METAc*BKT*NCHK
    int*   totals= sofs + (size_t)METAc * BKT * NCHK;    // METAc*BKT
    int*   bbase = totals + METAc * BKT;                 // METAc*BKT
    uint*  packed= (uint*)(bbase + METAc * BKT);         // METAc*Ee
    uint*  mid   = packed + (size_t)METAc * Ee;          // METAc*Ee
    ushort* esrc = (ushort*)(mid + (size_t)METAc * Ee);  // METAc*Ee
    uchar* t1    = (uchar*)(esrc + (size_t)METAc * Ee);  // nN*128 fp8
    ushort* r1   = (ushort*)(t1 + nN * 128);
    ushort* h    = r1 + nN * 128;
    uchar* t2    = (uchar*)(h + nN * 128);               // nN*64 fp8
    ushort* r2   = (ushort*)(t2 + nN * 64);
    ushort* Wcat1 = r2 + nN * 64;
    ushort* Wcat2 = Wcat1 + (size_t)METAc * 256 * 128;

    k_packhist<<<METAc * NCHK, 256, 0, stream>>>(ei, packed, ghist);
    k_bscan<<<METAc * BKT, 1024, 0, stream>>>(ghist, sofs, totals);
    k_bbase<<<METAc, 256, 0, stream>>>(totals, bbase);
    k_scatterP<<<METAc * NCHK, 256, 0, stream>>>(packed, sofs, bbase, mid);
    k_binb<<<METAc * BKT, 256, 0, stream>>>(mid, bbase, off, cnt, inv, esrc);
    k_wcat<<<(METAc * 384 * 128 + 255) / 256, 256, 0, stream>>>(W1l, W1r, W2l, W2r, Wcat1, Wcat2);

    k_mfma1<<<dim3((Nn + 127) / 128, METAc), 256, 0, stream>>>(meta_x, Wcat1, b1, t1, r1);
    k_agg_elu<<<(METAc * Nn / 8 + 255) / 256 * 64, 256, 0, stream>>>(t1, r1, off, cnt, inv, esrc, h);
    k_mfma2<<<dim3((Nn + 127) / 128, METAc), 256, 0, stream>>>(h, Wcat2, b2, t2, r2);
    k_agg_lsm<<<(METAc * Nn / 8 + 255) / 256 * 64, 256, 0, stream>>>(t2, r2, off, cnt, inv, esrc, out);
}

// Round 23
// 190.312 us; speedup vs baseline: 3.3085x; 1.0029x over previous
//
#include <hip/hip_runtime.h>

#define METAc 3
#define Nn 50000
#define Ee 640000
#define BKT 200      // dst buckets per graph
#define BN 250       // nodes per bucket (200*250 = 50000 exact)
#define NCHK 625     // 1024-edge chunks per graph (625*1024 = 640000 exact)
#define SEGCAP 4608  // LDS edge cap per bucket (mean 3200, sigma 57 -> +24 sigma)

typedef unsigned int uint;
typedef unsigned short ushort;
typedef unsigned char uchar;
typedef __attribute__((ext_vector_type(8))) short bf16x8;
typedef __attribute__((ext_vector_type(4))) float f32x4;
typedef __attribute__((ext_vector_type(2))) float f32x2;
typedef __attribute__((ext_vector_type(4))) uint uint4v;

#define CVT8LO(w) ((f32x2)__builtin_amdgcn_cvt_pk_f32_fp8((w), false))
#define CVT8HI(w) ((f32x2)__builtin_amdgcn_cvt_pk_f32_fp8((w), true))

__device__ __forceinline__ float bf2f(uint u16) {
    union { uint u; float f; } v; v.u = u16 << 16; return v.f;
}
__device__ __forceinline__ uint f2bf(float f) {
    union { float f; uint u; } v; v.f = f;
    return (v.u + 0x7fffu + ((v.u >> 16) & 1u)) >> 16;
}
__device__ __forceinline__ uchar f2fp8(float f) {
    return (uchar)(__builtin_amdgcn_cvt_pk_fp8_f32(f, f, 0u, false) & 0xffu);
}
__device__ __forceinline__ f32x2 up2(uint u) {
    union { uint2 u2; f32x2 f; } cv;
    cv.u2.x = u << 16;
    cv.u2.y = u & 0xffff0000u;
    return cv.f;
}
__device__ __forceinline__ f32x4 mfma16(bf16x8 a, bf16x8 b, f32x4 c) {
    return __builtin_amdgcn_mfma_f32_16x16x32_bf16(a, b, c, 0, 0, 0);
}
__device__ __forceinline__ uint4v nt_load4(const void* p) {
    return __builtin_nontemporal_load((const uint4v*)p);
}

// ===== 1) pack + per-chunk bucket histogram (no global atomics) =====
__global__ __launch_bounds__(256) void k_packhist(const int* __restrict__ ei,
                                                  uint* __restrict__ packed,
                                                  int* __restrict__ ghist) {
    const int m = blockIdx.x / NCHK;
    const int b = blockIdx.x - m * NCHK;
    const int t = threadIdx.x;
    __shared__ int hist[BKT];
    if (t < BKT) hist[t] = 0;
    __syncthreads();

    const int e4 = b * 256 + t;                 // uint4 index within graph
    const int* base = ei + (size_t)m * 2 * Ee;
    uint4v d = nt_load4(base + Ee + e4 * 4);
    uint4v s = nt_load4(base + e4 * 4);
    uint4v p;
    p.x = (s.x & 0xffffu) | (d.x << 16);
    p.y = (s.y & 0xffffu) | (d.y << 16);
    p.z = (s.z & 0xffffu) | (d.z << 16);
    p.w = (s.w & 0xffffu) | (d.w << 16);
    *(uint4v*)(packed + (size_t)m * Ee + e4 * 4) = p;
    atomicAdd(&hist[(int)(d.x) / BN], 1);
    atomicAdd(&hist[(int)(d.y) / BN], 1);
    atomicAdd(&hist[(int)(d.z) / BN], 1);
    atomicAdd(&hist[(int)(d.w) / BN], 1);
    __syncthreads();
    if (t < BKT) ghist[((size_t)m * NCHK + b) * BKT + t] = hist[t];
}

// ===== 2) per-(m,bucket) exclusive scan over chunks -> sofs, totals =====
__global__ __launch_bounds__(1024) void k_bscan(const int* __restrict__ ghist,
                                                int* __restrict__ sofs,
                                                int* __restrict__ totals) {
    const int m = blockIdx.x / BKT;
    const int k = blockIdx.x - m * BKT;
    const int t = threadIdx.x;
    __shared__ int sc[1024];
    int v = (t < NCHK) ? ghist[((size_t)m * NCHK + t) * BKT + k] : 0;
    sc[t] = v;
    __syncthreads();
    for (int st = 1; st < 1024; st <<= 1) {
        int add = (t >= st) ? sc[t - st] : 0;
        __syncthreads();
        sc[t] += add;
        __syncthreads();
    }
    if (t < NCHK) sofs[((size_t)m * BKT + k) * NCHK + t] = sc[t] - v;
    if (t == NCHK - 1) totals[m * BKT + k] = sc[t];
}

// ===== 3) per-graph scan of bucket totals -> bucket bases =====
__global__ __launch_bounds__(256) void k_bbase(const int* __restrict__ totals,
                                               int* __restrict__ bbase) {
    const int m = blockIdx.x;
    const int t = threadIdx.x;
    __shared__ int sc[256];
    int v = (t < BKT) ? totals[m * BKT + t] : 0;
    sc[t] = v;
    __syncthreads();
    for (int st = 1; st < 256; st <<= 1) {
        int add = (t >= st) ? sc[t - st] : 0;
        __syncthreads();
        sc[t] += add;
        __syncthreads();
    }
    if (t < BKT) bbase[m * BKT + t] = sc[t] - v;
}

// ===== 4) bucket partition: packed -> mid (LDS cursors, no global atomics) =====
__global__ __launch_bounds__(256) void k_scatterP(const uint* __restrict__ packed,
                                                  const int* __restrict__ sofs,
                                                  const int* __restrict__ bbase,
                                                  uint* __restrict__ mid) {
    const int m = blockIdx.x / NCHK;
    const int b = blockIdx.x - m * NCHK;
    const int t = threadIdx.x;
    __shared__ int curs[BKT];
    if (t < BKT)
        curs[t] = bbase[m * BKT + t] + sofs[((size_t)m * BKT + t) * NCHK + b];
    __syncthreads();

    const int e4 = b * 256 + t;
    uint4v p = *(const uint4v*)(packed + (size_t)m * Ee + e4 * 4);
    uint* mm = mid + (size_t)m * Ee;
    int kk, pos;
    kk = (int)(p.x >> 16) / BN; pos = atomicAdd(&curs[kk], 1); mm[pos] = p.x;
    kk = (int)(p.y >> 16) / BN; pos = atomicAdd(&curs[kk], 1); mm[pos] = p.y;
    kk = (int)(p.z >> 16) / BN; pos = atomicAdd(&curs[kk], 1); mm[pos] = p.z;
    kk = (int)(p.w >> 16) / BN; pos = atomicAdd(&curs[kk], 1); mm[pos] = p.w;
}

// ===== 5) per-bucket bin: mid -> esrc (coalesced), also off/cnt/inv =====
__global__ __launch_bounds__(256) void k_binb(const uint* __restrict__ mid,
                                              const int* __restrict__ bbase,
                                              int* __restrict__ off,
                                              int* __restrict__ cnt,
                                              float* __restrict__ inv,
                                              ushort* __restrict__ esrc) {
    const int m = blockIdx.x / BKT;
    const int k = blockIdx.x - m * BKT;
    const int t = threadIdx.x;
    const int n0 = k * BN;
    const int sbase = bbase[m * BKT + k];
    const int send = (k < BKT - 1) ? bbase[m * BKT + k + 1] : Ee;
    const int seglen = send - sbase;

    __shared__ uint seg[SEGCAP];
    __shared__ ushort outs[SEGCAP];
    __shared__ int lcnt[BN];
    __shared__ int lcur[BN];
    __shared__ int sc[256];

    const uint* mm = mid + (size_t)m * Ee + sbase;
    ushort* em = esrc + (size_t)m * Ee + sbase;
    const bool fits = seglen <= SEGCAP;

    if (fits)
        for (int i = t; i < seglen; i += 256) seg[i] = mm[i];
    if (t < BN) lcnt[t] = 0;
    __syncthreads();

    for (int i = t; i < seglen; i += 256) {
        uint p = fits ? seg[i] : mm[i];
        atomicAdd(&lcnt[(int)(p >> 16) - n0], 1);
    }
    __syncthreads();

    int v = (t < BN) ? lcnt[t] : 0;
    sc[t] = v;
    __syncthreads();
    for (int st = 1; st < 256; st <<= 1) {
        int add = (t >= st) ? sc[t - st] : 0;
        __syncthreads();
        sc[t] += add;
        __syncthreads();
    }
    if (t < BN) {
        int excl = sc[t] - v;
        lcur[t] = excl;
        int node = m * Nn + n0 + t;
        off[node] = sbase + excl;
        cnt[node] = v;
        inv[node] = 1.0f / fmaxf((float)v, 1.0f);
    }
    __syncthreads();

    if (fits) {
        for (int i = t; i < seglen; i += 256) {
            uint p = seg[i];
            int pos = atomicAdd(&lcur[(int)(p >> 16) - n0], 1);
            outs[pos] = (ushort)(p & 0xffffu);
        }
        __syncthreads();
        for (int i = t; i < seglen; i += 256) em[i] = outs[i];
    } else {
        for (int i = t; i < seglen; i += 256) {
            uint p = mm[i];
            int pos = atomicAdd(&lcur[(int)(p >> 16) - n0], 1);
            em[pos] = (ushort)(p & 0xffffu);
        }
    }
}

// ============ weight prep ============
__global__ __launch_bounds__(256) void k_wcat(
    const float* __restrict__ W1l, const float* __restrict__ W1r,
    const float* __restrict__ W2l, const float* __restrict__ W2r,
    ushort* __restrict__ Wcat1, ushort* __restrict__ Wcat2)
{
    int idx = blockIdx.x * 256 + threadIdx.x;
    if (idx >= METAc * 384 * 128) return;
    int m = idx / (384 * 128);
    int rem = idx - m * 384 * 128;
    int j = rem >> 7;
    int k = rem & 127;
    if (j < 256) {
        float v = (j < 128) ? W1l[((size_t)m * 128 + k) * 128 + j]
                            : W1r[((size_t)m * 128 + k) * 128 + (j - 128)];
        Wcat1[((size_t)m * 256 + j) * 128 + k] = (ushort)f2bf(v);
    } else {
        int j2 = j - 256;
        float v = (j2 < 64) ? W2l[((size_t)m * 128 + k) * 64 + j2]
                            : W2r[((size_t)m * 128 + k) * 64 + (j2 - 64)];
        Wcat2[((size_t)m * 128 + j2) * 128 + k] = (ushort)f2bf(v);
    }
}

// ============ MFMA GEMM1: t1 (fp8) and r1 (bf16, +b1) = x @ {W1l, W1r} ============
// K-split Bs (half tile, double-staged) -> LDS 52KB -> 3 blocks/CU.
// Epilogues staged: t1 -> Bs (16KB), r1 -> As (32KB, dead after z=1 MFMA).
__global__ __launch_bounds__(256) void k_mfma1(
    const float* __restrict__ x, const ushort* __restrict__ Wcat1,
    const float* __restrict__ b1, uchar* __restrict__ t1, ushort* __restrict__ r1)
{
    const int m = blockIdx.y;
    const int row0 = blockIdx.x * 128;
    const int tid = threadIdx.x;
    const int lane = tid & 63, w = tid >> 6;
    const int wr = w >> 1, wc = w & 1;

    __shared__ ushort As[128][136];   // 34.8KB: rows x full K
    __shared__ ushort Bs[128][72];    // 18.4KB: out-cols x half K

    const float* Am = x + (size_t)m * Nn * 128;

    #pragma unroll
    for (int i = 0; i < 16; i++) {
        int f4 = tid + i * 256;
        int row = f4 >> 5, c4 = f4 & 31;
        int gr = row0 + row; if (gr >= Nn) gr = Nn - 1;
        float4 v = *(const float4*)(Am + (size_t)gr * 128 + c4 * 4);
        uint lo = f2bf(v.x) | (f2bf(v.y) << 16);
        uint hi = f2bf(v.z) | (f2bf(v.w) << 16);
        *(uint2*)&As[row][c4 * 4] = make_uint2(lo, hi);
    }

    for (int z = 0; z < 2; z++) {
        const ushort* Bm = Wcat1 + ((size_t)m * 256 + (size_t)z * 128) * 128;

        f32x4 acc[4][4];
        #pragma unroll
        for (int i = 0; i < 4; i++)
            #pragma unroll
            for (int j = 0; j < 4; j++) acc[i][j] = (f32x4){0.f, 0.f, 0.f, 0.f};

        #pragma unroll
        for (int kh = 0; kh < 2; kh++) {
            __syncthreads();   // previous Bs consumers done (MFMA reads / flush)
            #pragma unroll
            for (int i = 0; i < 4; i++) {
                int c8 = tid + i * 256;
                int row = c8 >> 3, c = c8 & 7;
                *(bf16x8*)&Bs[row][c * 8] = *(const bf16x8*)(Bm + (size_t)row * 128 + kh * 64 + c * 8);
            }
            __syncthreads();
            #pragma unroll
            for (int ksl = 0; ksl < 2; ksl++) {
                int ks = kh * 2 + ksl;
                bf16x8 a[4], b[4];
                #pragma unroll
                for (int i = 0; i < 4; i++)
                    a[i] = *(const bf16x8*)&As[wr * 64 + i * 16 + (lane & 15)][ks * 32 + (lane >> 4) * 8];
                #pragma unroll
                for (int j = 0; j < 4; j++)
                    b[j] = *(const bf16x8*)&Bs[wc * 64 + j * 16 + (lane & 15)][ksl * 32 + (lane >> 4) * 8];
                #pragma unroll
                for (int i = 0; i < 4; i++)
                    #pragma unroll
                    for (int j = 0; j < 4; j++)
                        acc[i][j] = mfma16(a[i], b[j], acc[i][j]);
            }
        }

        __syncthreads();   // MFMA reads complete -> reuse LDS for staging
        if (z == 0) {
            uchar* stg = (uchar*)&Bs[0][0];   // 128x128 fp8 = 16KB <= 18.4KB
            #pragma unroll
            for (int j = 0; j < 4; j++) {
                int col = wc * 64 + j * 16 + (lane & 15);
                #pragma unroll
                for (int i = 0; i < 4; i++) {
                    #pragma unroll
                    for (int q = 0; q < 4; q++) {
                        int row = wr * 64 + i * 16 + (lane >> 4) * 4 + q;
                        stg[row * 128 + col] = f2fp8(acc[i][j][q]);
                    }
                }
            }
            __syncthreads();
            uchar* outp = t1 + (size_t)m * Nn * 128 + (size_t)row0 * 128;
            #pragma unroll
            for (int i = 0; i < 4; i++) {
                int o = (tid + i * 256) * 16;
                if (row0 + (o >> 7) < Nn)
                    *(uint4*)(outp + o) = *(const uint4*)(stg + o);
            }
        } else {
            ushort* stg = &As[0][0];   // 128x128 bf16 = 32KB <= 34.8KB (As dead)
            #pragma unroll
            for (int j = 0; j < 4; j++) {
                int col = wc * 64 + j * 16 + (lane & 15);
                float bias = b1[m * 128 + col];
                #pragma unroll
                for (int i = 0; i < 4; i++) {
                    #pragma unroll
                    for (int q = 0; q < 4; q++) {
                        int row = wr * 64 + i * 16 + (lane >> 4) * 4 + q;
                        stg[row * 128 + col] = (ushort)f2bf(acc[i][j][q] + bias);
                    }
                }
            }
            __syncthreads();
            ushort* outp = r1 + (size_t)m * Nn * 128 + (size_t)row0 * 128;
            #pragma unroll
            for (int i = 0; i < 8; i++) {
                int o = (tid + i * 256) * 8;   // ushort units, 16B granule
                if (row0 + (o >> 7) < Nn)
                    *(uint4*)(outp + o) = *(const uint4*)(stg + o);
            }
        }
    }
}

// ============ MFMA GEMM2: t2 (fp8) / r2 (bf16, +b2) = h @ Wcat2 ============
// K-split Bs; staged epilogue in As (t2 8KB at byte 0, r2 16KB at byte 8192).
__global__ __launch_bounds__(256) void k_mfma2(
    const ushort* __restrict__ h, const ushort* __restrict__ Wcat2,
    const float* __restrict__ b2, uchar* __restrict__ t2, ushort* __restrict__ r2)
{
    const int m = blockIdx.y;
    const int row0 = blockIdx.x * 128;
    const int tid = threadIdx.x;
    const int lane = tid & 63, w = tid >> 6;
    const int wr = w >> 1, wc = w & 1;

    __shared__ ushort As[128][136];
    __shared__ ushort Bs[128][72];

    const ushort* Am = h + (size_t)m * Nn * 128;
    const ushort* Bm = Wcat2 + (size_t)m * 128 * 128;

    #pragma unroll
    for (int i = 0; i < 8; i++) {
        int c8 = tid + i * 256;
        int row = c8 >> 4, c = c8 & 15;
        int gr = row0 + row; if (gr >= Nn) gr = Nn - 1;
        *(bf16x8*)&As[row][c * 8] = *(const bf16x8*)(Am + (size_t)gr * 128 + c * 8);
    }

    f32x4 acc[4][4];
    #pragma unroll
    for (int i = 0; i < 4; i++)
        #pragma unroll
        for (int j = 0; j < 4; j++) acc[i][j] = (f32x4){0.f, 0.f, 0.f, 0.f};

    #pragma unroll
    for (int kh = 0; kh < 2; kh++) {
        __syncthreads();
        #pragma unroll
        for (int i = 0; i < 4; i++) {
            int c8 = tid + i * 256;
            int row = c8 >> 3, c = c8 & 7;
            *(bf16x8*)&Bs[row][c * 8] = *(const bf16x8*)(Bm + (size_t)row * 128 + kh * 64 + c * 8);
        }
        __syncthreads();
        #pragma unroll
        for (int ksl = 0; ksl < 2; ksl++) {
            int ks = kh * 2 + ksl;
            bf16x8 a[4], b[4];
            #pragma unroll
            for (int i = 0; i < 4; i++)
                a[i] = *(const bf16x8*)&As[wr * 64 + i * 16 + (lane & 15)][ks * 32 + (lane >> 4) * 8];
            #pragma unroll
            for (int j = 0; j < 4; j++)
                b[j] = *(const bf16x8*)&Bs[wc * 64 + j * 16 + (lane & 15)][ksl * 32 + (lane >> 4) * 8];
            #pragma unroll
            for (int i = 0; i < 4; i++)
                #pragma unroll
                for (int j = 0; j < 4; j++)
                    acc[i][j] = mfma16(a[i], b[j], acc[i][j]);
        }
    }

    __syncthreads();   // As/Bs free -> staging in As
    uchar* stgb = (uchar*)&As[0][0];          // t2 fp8 tile: 128x64 = 8KB
    ushort* stgr = (ushort*)(stgb + 8192);    // r2 bf16 tile: 128x64 = 16KB
    #pragma unroll
    for (int j = 0; j < 4; j++) {
        int cl = j * 16 + (lane & 15);
        float bias = wc ? b2[m * 64 + cl] : 0.0f;
        #pragma unroll
        for (int i = 0; i < 4; i++) {
            #pragma unroll
            for (int q = 0; q < 4; q++) {
                int row = wr * 64 + i * 16 + (lane >> 4) * 4 + q;
                if (wc)
                    stgr[row * 64 + cl] = (ushort)f2bf(acc[i][j][q] + bias);
                else
                    stgb[row * 64 + cl] = f2fp8(acc[i][j][q]);
            }
        }
    }
    __syncthreads();
    uchar* ot = t2 + (size_t)m * Nn * 64 + (size_t)row0 * 64;
    ushort* orr = r2 + (size_t)m * Nn * 64 + (size_t)row0 * 64;
    #pragma unroll
    for (int i = 0; i < 2; i++) {       // t2: 8KB flush
        int o = (tid + i * 256) * 16;   // byte offset; row = o/64
        if (row0 + (o >> 6) < Nn)
            *(uint4*)(ot + o) = *(const uint4*)(stgb + o);
    }
    #pragma unroll
    for (int i = 0; i < 4; i++) {       // r2: 16KB flush
        int o = (tid + i * 256) * 8;    // ushort offset; row = o/64
        if (row0 + (o >> 6) < Nn)
            *(uint4*)(orr + o) = *(const uint4*)(stgr + o);
    }
}

// ============ agg1: h = ELU(mean-gather(t1 fp8) + r1), bf16 out ============
// One 8-lane group per node; 4-edge-deep gather pipeline (4 loads in flight).
__global__ __launch_bounds__(256) void k_agg_elu(
    const uchar* __restrict__ t1, const ushort* __restrict__ r1,
    const int* __restrict__ off, const int* __restrict__ cnt,
    const float* __restrict__ inv, const ushort* __restrict__ esrc,
    ushort* __restrict__ h)
{
    int lane = threadIdx.x & 63;
    int grp = lane >> 3;
    int sub = lane & 7;
    int node = ((blockIdx.x * 256 + threadIdx.x) >> 6) * 8 + grp;
    if (node >= METAc * Nn) return;
    int m = node / Nn, n = node - m * Nn;
    int start = off[m * Nn + n];
    int c = cnt[m * Nn + n];
    const ushort* es = esrc + (size_t)m * Ee + start;
    const uchar* tm = t1 + (size_t)m * Nn * 128;

    f32x2 a[8];
    #pragma unroll
    for (int k = 0; k < 8; k++) a[k] = (f32x2){0.f, 0.f};

    int e = 0;
    for (; e + 3 < c; e += 4) {
        int s0 = es[e], s1 = es[e + 1], s2 = es[e + 2], s3 = es[e + 3];
        uint4 v0 = *(const uint4*)(tm + (size_t)s0 * 128 + sub * 16);
        uint4 v1 = *(const uint4*)(tm + (size_t)s1 * 128 + sub * 16);
        uint4 v2 = *(const uint4*)(tm + (size_t)s2 * 128 + sub * 16);
        uint4 v3 = *(const uint4*)(tm + (size_t)s3 * 128 + sub * 16);
        a[0] += CVT8LO(v0.x); a[1] += CVT8HI(v0.x);
        a[2] += CVT8LO(v0.y); a[3] += CVT8HI(v0.y);
        a[4] += CVT8LO(v0.z); a[5] += CVT8HI(v0.z);
        a[6] += CVT8LO(v0.w); a[7] += CVT8HI(v0.w);
        a[0] += CVT8LO(v1.x); a[1] += CVT8HI(v1.x);
        a[2] += CVT8LO(v1.y); a[3] += CVT8HI(v1.y);
        a[4] += CVT8LO(v1.z); a[5] += CVT8HI(v1.z);
        a[6] += CVT8LO(v1.w); a[7] += CVT8HI(v1.w);
        a[0] += CVT8LO(v2.x); a[1] += CVT8HI(v2.x);
        a[2] += CVT8LO(v2.y); a[3] += CVT8HI(v2.y);
        a[4] += CVT8LO(v2.z); a[5] += CVT8HI(v2.z);
        a[6] += CVT8LO(v2.w); a[7] += CVT8HI(v2.w);
        a[0] += CVT8LO(v3.x); a[1] += CVT8HI(v3.x);
        a[2] += CVT8LO(v3.y); a[3] += CVT8HI(v3.y);
        a[4] += CVT8LO(v3.z); a[5] += CVT8HI(v3.z);
        a[6] += CVT8LO(v3.w); a[7] += CVT8HI(v3.w);
    }
    for (; e < c; e++) {
        int s0 = es[e];
        uint4 v0 = *(const uint4*)(tm + (size_t)s0 * 128 + sub * 16);
        a[0] += CVT8LO(v0.x); a[1] += CVT8HI(v0.x);
        a[2] += CVT8LO(v0.y); a[3] += CVT8HI(v0.y);
        a[4] += CVT8LO(v0.z); a[5] += CVT8HI(v0.z);
        a[6] += CVT8LO(v0.w); a[7] += CVT8HI(v0.w);
    }

    float iv = inv[m * Nn + n];
    const uint* rrow = (const uint*)(r1 + ((size_t)m * Nn + n) * 128);
    uint4 rv0 = *(const uint4*)(rrow + sub * 8);
    uint4 rv1 = *(const uint4*)(rrow + sub * 8 + 4);
    uint rw[8] = {rv0.x, rv0.y, rv0.z, rv0.w, rv1.x, rv1.y, rv1.z, rv1.w};
    uint o[8];
    #pragma unroll
    for (int k = 0; k < 8; k++) {
        float z0 = a[k].x * iv + bf2f(rw[k] & 0xffffu);
        float z1 = a[k].y * iv + bf2f(rw[k] >> 16);
        z0 = z0 > 0.0f ? z0 : (__expf(z0) - 1.0f);
        z1 = z1 > 0.0f ? z1 : (__expf(z1) - 1.0f);
        o[k] = f2bf(z0) | (f2bf(z1) << 16);
    }
    uint* hrow = (uint*)(h + ((size_t)m * Nn + n) * 128) + sub * 8;
    *(uint4*)hrow       = make_uint4(o[0], o[1], o[2], o[3]);
    *(uint4*)(hrow + 4) = make_uint4(o[4], o[5], o[6], o[7]);
}

// ============ agg2: out = log_softmax(mean-gather(t2 fp8) + r2) ============
// One 8-lane group per node; t2 row = 64B fp8 -> uint2/lane; 4-deep pipeline.
__global__ __launch_bounds__(256) void k_agg_lsm(
    const uchar* __restrict__ t2, const ushort* __restrict__ r2,
    const int* __restrict__ off, const int* __restrict__ cnt,
    const float* __restrict__ inv, const ushort* __restrict__ esrc,
    float* __restrict__ out)
{
    int lane = threadIdx.x & 63;
    int grp = lane >> 3;
    int sub = lane & 7;       // 8B chunk = 8 fp8 cols
    int node = ((blockIdx.x * 256 + threadIdx.x) >> 6) * 8 + grp;
    if (node >= METAc * Nn) return;
    int m = node / Nn, n = node - m * Nn;
    int start = off[m * Nn + n];
    int c = cnt[m * Nn + n];
    const ushort* es = esrc + (size_t)m * Ee + start;
    const uchar* tm = t2 + (size_t)m * Nn * 64;

    f32x2 a[4];
    #pragma unroll
    for (int k = 0; k < 4; k++) a[k] = (f32x2){0.f, 0.f};

    int e = 0;
    for (; e + 3 < c; e += 4) {
        int s0 = es[e], s1 = es[e + 1], s2 = es[e + 2], s3 = es[e + 3];
        uint2 v0 = *(const uint2*)(tm + (size_t)s0 * 64 + sub * 8);
        uint2 v1 = *(const uint2*)(tm + (size_t)s1 * 64 + sub * 8);
        uint2 v2 = *(const uint2*)(tm + (size_t)s2 * 64 + sub * 8);
        uint2 v3 = *(const uint2*)(tm + (size_t)s3 * 64 + sub * 8);
        a[0] += CVT8LO(v0.x); a[1] += CVT8HI(v0.x);
        a[2] += CVT8LO(v0.y); a[3] += CVT8HI(v0.y);
        a[0] += CVT8LO(v1.x); a[1] += CVT8HI(v1.x);
        a[2] += CVT8LO(v1.y); a[3] += CVT8HI(v1.y);
        a[0] += CVT8LO(v2.x); a[1] += CVT8HI(v2.x);
        a[2] += CVT8LO(v2.y); a[3] += CVT8HI(v2.y);
        a[0] += CVT8LO(v3.x); a[1] += CVT8HI(v3.x);
        a[2] += CVT8LO(v3.y); a[3] += CVT8HI(v3.y);
    }
    for (; e < c; e++) {
        int s0 = es[e];
        uint2 v0 = *(const uint2*)(tm + (size_t)s0 * 64 + sub * 8);
        a[0] += CVT8LO(v0.x); a[1] += CVT8HI(v0.x);
        a[2] += CVT8LO(v0.y); a[3] += CVT8HI(v0.y);
    }

    float iv = inv[m * Nn + n];
    uint4 rv = *(const uint4*)(r2 + ((size_t)m * Nn + n) * 64 + sub * 8);
    uint rr[4] = {rv.x, rv.y, rv.z, rv.w};
    float z[8];
    #pragma unroll
    for (int k = 0; k < 4; k++) {
        z[2 * k]     = a[k].x * iv + bf2f(rr[k] & 0xffffu);
        z[2 * k + 1] = a[k].y * iv + bf2f(rr[k] >> 16);
    }
    float mx = z[0];
    #pragma unroll
    for (int k = 1; k < 8; k++) mx = fmaxf(mx, z[k]);
    #pragma unroll
    for (int o = 1; o <= 4; o <<= 1) mx = fmaxf(mx, __shfl_xor(mx, o));
    float s = 0.0f;
    #pragma unroll
    for (int k = 0; k < 8; k++) s += __expf(z[k] - mx);
    #pragma unroll
    for (int o = 1; o <= 4; o <<= 1) s += __shfl_xor(s, o);
    float lse = mx + __logf(s);
    float* op = out + ((size_t)m * Nn + n) * 64 + sub * 8;
    *(float4*)op       = make_float4(z[0] - lse, z[1] - lse, z[2] - lse, z[3] - lse);
    *(float4*)(op + 4) = make_float4(z[4] - lse, z[5] - lse, z[6] - lse, z[7] - lse);
}

extern "C" void kernel_launch(void* const* d_in, const int* in_sizes, int n_in,
                              void* d_out, int out_size, void* d_ws, size_t ws_size,
                              hipStream_t stream) {
    const float* meta_x = (const float*)d_in[0];
    const int*   ei     = (const int*)d_in[1];
    const float* W1l    = (const float*)d_in[2];
    const float* W1r    = (const float*)d_in[3];
    const float* b1     = (const float*)d_in[4];
    const float* W2l    = (const float*)d_in[5];
    const float* W2r    = (const float*)d_in[6];
    const float* b2     = (const float*)d_in[7];
    float* out = (float*)d_out;

    const size_t nN = (size_t)METAc * Nn;

    float* inv   = (float*)d_ws;                         // nN
    int*   cnt   = (int*)(inv + nN);                     // nN
    int*   off   = cnt + nN;                             // nN
    int*   ghist = off + nN;                             // METAc*NCHK*BKT
    int*   sofs  = ghist + (size_t)METAc * NCHK * BKT;   // METAc*BKT*NCHK
    int*   totals= sofs + (size_t)METAc * BKT * NCHK;    // METAc*BKT
    int*   bbase = totals + METAc * BKT;                 // METAc*BKT
    uint*  packed= (uint*)(bbase + METAc * BKT);         // METAc*Ee
    uint*  mid   = packed + (size_t)METAc * Ee;          // METAc*Ee
    ushort* esrc = (ushort*)(mid + (size_t)METAc * Ee);  // METAc*Ee
    uchar* t1    = (uchar*)(esrc + (size_t)METAc * Ee);  // nN*128 fp8
    ushort* r1   = (ushort*)(t1 + nN * 128);
    ushort* h    = r1 + nN * 128;
    uchar* t2    = (uchar*)(h + nN * 128);               // nN*64 fp8
    ushort* r2   = (ushort*)(t2 + nN * 64);
    ushort* Wcat1 = r2 + nN * 64;
    ushort* Wcat2 = Wcat1 + (size_t)METAc * 256 * 128;

    k_packhist<<<METAc * NCHK, 256, 0, stream>>>(ei, packed, ghist);
    k_bscan<<<METAc * BKT, 1024, 0, stream>>>(ghist, sofs, totals);
    k_bbase<<<METAc, 256, 0, stream>>>(totals, bbase);
    k_scatterP<<<METAc * NCHK, 256, 0, stream>>>(packed, sofs, bbase, mid);
    k_binb<<<METAc * BKT, 256, 0, stream>>>(mid, bbase, off, cnt, inv, esrc);
    k_wcat<<<(METAc * 384 * 128 + 255) / 256, 256, 0, stream>>>(W1l, W1r, W2l, W2r, Wcat1, Wcat2);

    k_mfma1<<<dim3((Nn + 127) / 128, METAc), 256, 0, stream>>>(meta_x, Wcat1, b1, t1, r1);
    k_agg_elu<<<(METAc * Nn / 8 + 255) / 256 * 64, 256, 0, stream>>>(t1, r1, off, cnt, inv, esrc, h);
    k_mfma2<<<dim3((Nn + 127) / 128, METAc), 256, 0, stream>>>(h, Wcat2, b2, t2, r2);
    k_agg_lsm<<<(METAc * Nn / 8 + 255) / 256 * 64, 256, 0, stream>>>(t2, r2, off, cnt, inv, esrc, out);
}